// Round 5
// baseline (2114.972 us; speedup 1.0000x reference)
//
#include <hip/hip_runtime.h>
#include <hip/hip_bf16.h>
#include <hip/hip_cooperative_groups.h>

namespace cg = cooperative_groups;

#define N_NODES 30000
#define N_EDGES 480000
#define NFEAT 92
#define EFEAT 50
#define D1 64
#define ZD 178
#define NL 3
#define NG 256
#define BN_EPS 1e-5f
#define NTILES (N_EDGES / 16)                // 30000 edge tiles
#define SCAN_BLOCKS ((N_NODES + 255) / 256)  // 118
#define BUILD_CHUNKS 1875                    // E / 256
#define NB 1024                              // persistent grid: 4 blocks/CU x 256 CUs
#define SMEM_BYTES 17408                     // max over phases (edgemm mlds)

typedef __attribute__((ext_vector_type(8))) short bf16x8;
typedef __attribute__((ext_vector_type(8))) unsigned short u16x8;
typedef __attribute__((ext_vector_type(4))) unsigned short u16x4;
typedef __attribute__((ext_vector_type(4))) float f32x4;

struct KParams {
  const float *x, *ea, *lin0_w, *lin0_b, *conv_wf, *conv_bf, *conv_ws, *conv_bs;
  const float *bn_gamma, *bn_beta, *lin1_w, *lin1_b, *fc_w, *fc_b, *lin2_w, *lin2_b;
  const int *ei, *batch;
  float *h0, *h1, *aggrA, *aggrB, *stat, *invc, *out;
  unsigned short *projd, *projs, *eapb, *Bp;
  int *cnt, *lpre, *ptot, *wptr, *grp;
  int2 *ds2;
};

static __device__ __forceinline__ unsigned short f2bf(float v) {
  __hip_bfloat16 b = __float2bfloat16(v);
  return *(unsigned short*)&b;
}
static __device__ __forceinline__ float bfu(unsigned short u) {
  union { unsigned int i; float f; } c;
  c.i = ((unsigned int)u) << 16;
  return c.f;
}

// ---------------- nodeproj body (identical math to 621us baseline) ----------
static __device__ __forceinline__ void nodeproj_body(
    int blk0, int nblk, const float* __restrict__ hin, float* __restrict__ hout,
    const float* __restrict__ wfp, const float* __restrict__ wsm,
    unsigned short* __restrict__ projd_pk, unsigned short* __restrict__ projs_pk,
    const float* __restrict__ aggr, float* __restrict__ aggr_z,
    const float* __restrict__ invc, const float* __restrict__ musum,
    const float* __restrict__ sqsum, const float* __restrict__ gamma,
    const float* __restrict__ beta, int do_bn, float (*hl)[64]) {
  const int lane = threadIdx.x & 63;
  const int w = threadIdx.x >> 6;  // 0..3
  const float* W = (w < 2) ? wfp : wsm;
  const int roff = (w & 1) * 64;  // 0=dst rows, 1=src rows
  float wreg[D1];
#pragma unroll
  for (int k = 0; k < D1; ++k) wreg[k] = W[(size_t)(roff + k) * D1 + lane];
  unsigned short* pk = (w & 1) ? projs_pk : projd_pk;
  const int slot = (w < 2) ? 0 : 4;  // Wf -> lo4, Ws -> hi4
  const int poff = (lane >> 2) * 8 + (lane & 3) + slot;
  float r = 0.0f, sh = 0.0f;
  if (do_bn) {
    const float mu = musum[lane] * (1.0f / N_NODES);
    const float var = sqsum[lane] * (1.0f / N_NODES) - mu * mu;
    r = gamma[lane] * rsqrtf(var + BN_EPS);
    sh = beta[lane] - mu * r;
  }
  for (int i = blk0; i < N_NODES; i += nblk) {
    float hv = hin[(size_t)i * D1 + lane];
    if (do_bn) {
      const float av = aggr[(size_t)i * D1 + lane] * invc[i];
      hv = fmaxf(hv + fmaf(av, r, sh), 0.0f);
      if (w == 0) hout[(size_t)i * D1 + lane] = hv;
    }
    if (w == 1 && aggr_z) aggr_z[(size_t)i * D1 + lane] = 0.0f;  // zero for next edgemm
    hl[w][lane] = hv;
    __builtin_amdgcn_wave_barrier();
    const float4* hr = (const float4*)&hl[w][0];
    float acc = 0.0f;
#pragma unroll
    for (int k4 = 0; k4 < D1 / 4; ++k4) {
      const float4 v = hr[k4];
      acc = fmaf(v.x, wreg[4 * k4 + 0], acc);
      acc = fmaf(v.y, wreg[4 * k4 + 1], acc);
      acc = fmaf(v.z, wreg[4 * k4 + 2], acc);
      acc = fmaf(v.w, wreg[4 * k4 + 3], acc);
    }
    pk[(size_t)i * 128 + poff] = f2bf(acc);
    __builtin_amdgcn_wave_barrier();
  }
}

// ---------------- P0: lin0 + cnt + wprep + zero(aggrA, stat) ----------------
static __device__ void phase0(const KParams& p) {
  const int tid = threadIdx.x, bid = blockIdx.x;
  const int lane = tid & 63, wv = tid >> 6;
  const int gw = bid * 4 + wv, nw = gridDim.x * 4;
  const int gt = bid * 256 + tid, nt = gridDim.x * 256;
  {  // lin0
    float wreg[NFEAT];
#pragma unroll
    for (int k = 0; k < NFEAT; ++k) wreg[k] = p.lin0_w[k * D1 + lane];
    const float bj = p.lin0_b[lane];
    for (int i = gw; i < N_NODES; i += nw) {
      const float2* xr = (const float2*)(p.x + (size_t)i * NFEAT);
      float acc = bj;
#pragma unroll
      for (int k = 0; k < NFEAT / 2; ++k) {
        const float2 v = xr[k];
        acc = fmaf(v.x, wreg[2 * k], acc);
        acc = fmaf(v.y, wreg[2 * k + 1], acc);
      }
      p.h0[(size_t)i * D1 + lane] = fmaxf(acc, 0.0f);
    }
  }
  for (int e = gt; e < N_EDGES; e += nt) atomicAdd(&p.cnt[p.ei[N_EDGES + e]], 1);
  for (int idx = gt; idx < NL * 16 * 64 * 8; idx += nt) {  // wprep
    const int j = idx & 7;
    const int ln = (idx >> 3) & 63;
    const int frag = (idx >> 9) & 15;  // (m*2+t)*4+n
    const int l = idx >> 13;
    const int n = frag & 3;
    const int t = (frag >> 2) & 1;
    const int m = frag >> 3;
    const int k = t * 32 + (ln >> 4) * 8 + j;
    const int feat = (ln & 15) * 4 + n;
    float v = 0.0f;
    if (k < EFEAT) {
      const float* W = (m == 0) ? p.conv_wf : p.conv_ws;
      v = W[(size_t)l * ZD * D1 + (size_t)(128 + k) * D1 + feat];
    }
    p.Bp[idx] = f2bf(v);
  }
  for (int i = gt; i < N_NODES * D1; i += nt) p.aggrA[i] = 0.0f;
  if (bid == 0 && tid < NL * 128) p.stat[tid] = 0.0f;
}

// ---------------- P1/P2: scans ----------------
static __device__ void phase_scan1(const KParams& p, char* smem) {
  const int bid = blockIdx.x;
  if (bid >= SCAN_BLOCKS) return;
  int* bs = (int*)smem;
  const int t = threadIdx.x;
  const int idx = bid * 256 + t;
  const int v = (idx < N_NODES) ? p.cnt[idx] : 0;
  bs[t] = v;
  __syncthreads();
  for (int off = 1; off < 256; off <<= 1) {
    int u = (t >= off) ? bs[t - off] : 0;
    __syncthreads();
    bs[t] += u;
    __syncthreads();
  }
  if (idx < N_NODES) p.lpre[idx] = bs[t] - v;
  if (t == 255) p.ptot[bid] = bs[255];
}

static __device__ void phase_scan23(const KParams& p, char* smem) {
  const int bid = blockIdx.x;
  if (bid >= SCAN_BLOCKS) return;
  int* bs = (int*)smem;
  const int t = threadIdx.x;
  if (t < 128) bs[t] = (t < SCAN_BLOCKS) ? p.ptot[t] : 0;
  __syncthreads();
  for (int off = 1; off < 128; off <<= 1) {
    int u = 0;
    if (t < 128 && t >= off) u = bs[t - off];
    __syncthreads();
    if (t < 128 && t >= off) bs[t] += u;
    __syncthreads();
  }
  const int idx = bid * 256 + t;
  if (idx >= N_NODES) return;
  const int bb = idx >> 8;
  const int boff = (bb == 0) ? 0 : bs[bb - 1];
  p.wptr[idx] = boff + p.lpre[idx];
  p.invc[idx] = 1.0f / fmaxf((float)p.cnt[idx], 1.0f);
  const int bt = p.batch[idx];
  if (idx == 0)
    for (int g = 0; g <= bt; ++g) p.grp[g] = 0;
  else {
    const int pb = p.batch[idx - 1];
    for (int g = pb + 1; g <= bt; ++g) p.grp[g] = idx;
  }
  if (idx == N_NODES - 1)
    for (int g = bt + 1; g <= NG; ++g) p.grp[g] = N_NODES;
}

// ---------------- P3: CSR scatter + bf16 pack (chunked) + nodeproj0 ---------
static __device__ void phase3(const KParams& p, char* smem) {
  int* lpos = (int*)smem;                          // [0,1KB)
  float (*hl)[64] = (float(*)[64])(smem + 1024);   // [1KB,2KB)
  const int tid = threadIdx.x, bid = blockIdx.x;
  for (int c = bid; c < BUILD_CHUNKS; c += gridDim.x) {
    const int e0 = c * 256;
    {
      const int e = e0 + tid;
      const int d = p.ei[N_EDGES + e];
      const int pos = atomicAdd(&p.wptr[d], 1);
      p.ds2[pos] = make_int2(d, p.ei[e]);
      lpos[tid] = pos;
    }
    __syncthreads();
    const int l16 = tid & 15;
    const int sub = tid >> 4;
#pragma unroll
    for (int r = 0; r < 16; ++r) {
      const int eb = r * 16 + sub;
      const size_t ge = e0 + eb;
      const int pos = lpos[eb];
      unsigned short o0 = 0, o1 = 0, o2 = 0, o3 = 0;
      if (l16 < 12) {
        const float4 v = *(const float4*)(p.ea + ge * EFEAT + l16 * 4);
        o0 = f2bf(v.x); o1 = f2bf(v.y); o2 = f2bf(v.z); o3 = f2bf(v.w);
      } else if (l16 == 12) {
        const float2 v = *(const float2*)(p.ea + ge * EFEAT + 48);
        o0 = f2bf(v.x); o1 = f2bf(v.y);
      }
      u16x4 st;
      st[0] = o0; st[1] = o1; st[2] = o2; st[3] = o3;
      *(u16x4*)(p.eapb + ((size_t)pos << 6) + l16 * 4) = st;
    }
    __syncthreads();
  }
  nodeproj_body(bid, gridDim.x, p.h0, nullptr, p.conv_wf, p.conv_ws, p.projd, p.projs,
                nullptr, nullptr, nullptr, nullptr, nullptr, nullptr, nullptr, 0, hl);
}

// ---------------- edgemm phase (R0 1-tile body, grid-strided) ----------------
static __device__ void phase_edge(const KParams& p, int l, char* smem) {
  float (*mlds)[16][68] = (float(*)[16][68])smem;
  const int tid = threadIdx.x, bid = blockIdx.x;
  const int lane = tid & 63, wv = tid >> 6;
  const int col = lane & 15, quad = lane >> 4;
  const unsigned short* Bpl = p.Bp + (size_t)l * 16 * 64 * 8;
  const float* bfp = p.conv_bf + (size_t)l * D1;
  const float* bsp = p.conv_bs + (size_t)l * D1;
  float* aggr = (l == 1) ? p.aggrB : p.aggrA;

  bf16x8 Bf[2][2][4];
#pragma unroll
  for (int m = 0; m < 2; ++m)
#pragma unroll
    for (int tt = 0; tt < 2; ++tt)
#pragma unroll
      for (int n = 0; n < 4; ++n)
        Bf[m][tt][n] = *(const bf16x8*)(Bpl + ((((m * 2 + tt) * 4 + n) * 64 + lane) * 8));
  const f32x4 bf4 = *(const f32x4*)(bfp + col * 4);
  const f32x4 bs4 = *(const f32x4*)(bsp + col * 4);

  const int gw = bid * 4 + wv, nw = gridDim.x * 4;
  for (int t = gw; t < NTILES; t += nw) {
    const int base = t * 16;
    const int4 p01 = *(const int4*)(p.ds2 + base + quad * 4);
    const int4 p23 = *(const int4*)(p.ds2 + base + quad * 4 + 2);
    const int dr[4] = {p01.x, p01.z, p23.x, p23.z};
    const int sr[4] = {p01.y, p01.w, p23.y, p23.w};
    const bf16x8 Af0 = *(const bf16x8*)(p.eapb + ((size_t)(base + col) << 6) + quad * 8);
    const bf16x8 Af1 = *(const bf16x8*)(p.eapb + ((size_t)(base + col) << 6) + 32 + quad * 8);

    f32x4 aF[4], aS[4];
#pragma unroll
    for (int r = 0; r < 4; ++r) {
      const u16x8 pd = *(const u16x8*)(p.projd + (size_t)dr[r] * 128 + col * 8);
      const u16x8 ss = *(const u16x8*)(p.projs + (size_t)sr[r] * 128 + col * 8);
#pragma unroll
      for (int n = 0; n < 4; ++n) {
        aF[n][r] = bfu(pd[n]) + bfu(ss[n]) + bf4[n];
        aS[n][r] = bfu(pd[n + 4]) + bfu(ss[n + 4]) + bs4[n];
      }
    }
#pragma unroll
    for (int n = 0; n < 4; ++n) {
      aF[n] = __builtin_amdgcn_mfma_f32_16x16x32_bf16(Af0, Bf[0][0][n], aF[n], 0, 0, 0);
      aF[n] = __builtin_amdgcn_mfma_f32_16x16x32_bf16(Af1, Bf[0][1][n], aF[n], 0, 0, 0);
      aS[n] = __builtin_amdgcn_mfma_f32_16x16x32_bf16(Af0, Bf[1][0][n], aS[n], 0, 0, 0);
      aS[n] = __builtin_amdgcn_mfma_f32_16x16x32_bf16(Af1, Bf[1][1][n], aS[n], 0, 0, 0);
    }
#pragma unroll
    for (int r = 0; r < 4; ++r) {
      f32x4 mv;
#pragma unroll
      for (int n = 0; n < 4; ++n) {
        const float af = aF[n][r];
        const float as = aS[n][r];
        const float sg = __builtin_amdgcn_rcpf(1.0f + __expf(-af));
        const float sp = fmaxf(as, 0.0f) + __logf(1.0f + __expf(-fabsf(as)));
        mv[n] = sg * sp;
      }
      *(f32x4*)&mlds[wv][quad * 4 + r][col * 4] = mv;
    }
    __builtin_amdgcn_wave_barrier();
    float sum = 0.0f;
    int dcur = p.ds2[base].x;
#pragma unroll
    for (int q = 0; q < 16; ++q) {
      sum += mlds[wv][q][lane];
      const int dnxt = (q < 15) ? p.ds2[base + q + 1].x : -1;
      if (dnxt != dcur) {
        atomicAdd(&aggr[(size_t)dcur * D1 + lane], sum);
        sum = 0.0f;
        dcur = dnxt;
      }
    }
    __builtin_amdgcn_wave_barrier();
  }
}

// ---------------- stats phase ----------------
static __device__ void phase_stats(const KParams& p, int l, char* smem) {
  float* ls = (float*)smem;
  float* lq = ls + 256;
  const int tid = threadIdx.x, bid = blockIdx.x;
  const int j = tid & 63;
  const float* aggr = (l == 1) ? p.aggrB : p.aggrA;
  float* st = p.stat + (size_t)l * 128;
  const int rid = bid * 4 + (tid >> 6);
  const int rstr = gridDim.x * 4;
  float s = 0.0f, sq = 0.0f;
  for (int i = rid; i < N_NODES; i += rstr) {
    const float v = aggr[(size_t)i * D1 + j] * p.invc[i];
    s += v;
    sq = fmaf(v, v, sq);
  }
  ls[tid] = s;
  lq[tid] = sq;
  __syncthreads();
  if (tid < 64) {
    s = ls[j] + ls[64 + j] + ls[128 + j] + ls[192 + j];
    sq = lq[j] + lq[64 + j] + lq[128 + j] + lq[192 + j];
    atomicAdd(&st[j], s);
    atomicAdd(&st[64 + j], sq);
  }
  __syncthreads();
}

// ---------------- nodeproj_{l+1} phase (BN of layer l) ----------------
static __device__ void phase_np(const KParams& p, int l, char* smem) {
  float (*hl)[64] = (float(*)[64])smem;
  const float* ag = (l == 1) ? p.aggrB : p.aggrA;
  float* agz = (l == 0) ? p.aggrB : p.aggrA;
  const float* hin = (l == 0) ? p.h0 : p.h1;
  float* hout = (l == 0) ? p.h1 : p.h0;
  nodeproj_body(blockIdx.x, gridDim.x, hin, hout,
                p.conv_wf + (size_t)(l + 1) * ZD * D1, p.conv_ws + (size_t)(l + 1) * ZD * D1,
                p.projd, p.projs, ag, agz, p.invc,
                p.stat + (size_t)l * 128, p.stat + (size_t)l * 128 + 64,
                p.bn_gamma + (size_t)l * D1, p.bn_beta + (size_t)l * D1, 1, hl);
}

// ---------------- pool + MLP phase (final BN layer 2) ----------------
static __device__ void phase_pool(const KParams& p, char* smem) {
  const int g = blockIdx.x;
  if (g >= NG) return;
  float (*red)[64] = (float(*)[64])smem;       // 1KB
  float* vin = (float*)(smem + 1024);          // 256B
  const int lane = threadIdx.x & 63;
  const int wv = threadIdx.x >> 6;
  const float* st = p.stat + 2 * 128;
  const float mu = st[lane] * (1.0f / N_NODES);
  const float var = st[64 + lane] * (1.0f / N_NODES) - mu * mu;
  const float r = p.bn_gamma[2 * D1 + lane] * rsqrtf(var + BN_EPS);
  const float sh = p.bn_beta[2 * D1 + lane] - mu * r;
  const int s = p.grp[g], e = p.grp[g + 1];
  float acc = 0.0f;
  for (int i = s + wv; i < e; i += 4) {
    const float hv = p.h0[(size_t)i * D1 + lane];
    const float av = p.aggrA[(size_t)i * D1 + lane] * p.invc[i];
    acc += fmaxf(hv + fmaf(av, r, sh), 0.0f);
  }
  red[wv][lane] = acc;
  __syncthreads();
  const int j = threadIdx.x;
  float v = 0.0f;
  if (j < 64) {
    const float inv = 1.0f / fmaxf((float)(e - s), 1.0f);
    v = (red[0][j] + red[1][j] + red[2][j] + red[3][j]) * inv;
  }
  for (int layer = 0; layer < 3; ++layer) {
    if (j < 64) vin[j] = v;
    __syncthreads();
    if (j < 64) {
      const float* W;
      const float* B;
      if (layer == 0) { W = p.lin1_w; B = p.lin1_b; }
      else { W = p.fc_w + (size_t)(layer - 1) * D1 * D1; B = p.fc_b + (size_t)(layer - 1) * D1; }
      float a2 = B[j];
#pragma unroll 16
      for (int k = 0; k < D1; ++k) a2 = fmaf(vin[k], W[k * D1 + j], a2);
      v = fmaxf(a2, 0.0f);
    }
    __syncthreads();
  }
  if (j < 64) {
    float pr = v * p.lin2_w[j];
#pragma unroll
    for (int off = 32; off > 0; off >>= 1) pr += __shfl_down(pr, off);
    if (j == 0) p.out[g] = pr + p.lin2_b[0];
  }
}

// ---------------- persistent cooperative mega-kernel ----------------
__global__ void __launch_bounds__(256, 4) k_mega(KParams p) {
  __shared__ __align__(16) char smem[SMEM_BYTES];
  cg::grid_group grid = cg::this_grid();
  phase0(p);                 grid.sync();
  phase_scan1(p, smem);      grid.sync();
  phase_scan23(p, smem);     grid.sync();
  phase3(p, smem);           grid.sync();
  for (int l = 0; l < NL; ++l) {
    phase_edge(p, l, smem);  grid.sync();
    phase_stats(p, l, smem); grid.sync();
    if (l < NL - 1) { phase_np(p, l, smem); grid.sync(); }
  }
  phase_pool(p, smem);
}

// ---------------- fallback wrappers (same phases, separate dispatches) ------
__global__ void __launch_bounds__(256) k_w0(KParams p) { phase0(p); }
__global__ void __launch_bounds__(256) k_ws1(KParams p) {
  __shared__ __align__(16) char smem[SMEM_BYTES]; phase_scan1(p, smem);
}
__global__ void __launch_bounds__(256) k_ws2(KParams p) {
  __shared__ __align__(16) char smem[SMEM_BYTES]; phase_scan23(p, smem);
}
__global__ void __launch_bounds__(256) k_w3(KParams p) {
  __shared__ __align__(16) char smem[SMEM_BYTES]; phase3(p, smem);
}
__global__ void __launch_bounds__(256) k_we(KParams p, int l) {
  __shared__ __align__(16) char smem[SMEM_BYTES]; phase_edge(p, l, smem);
}
__global__ void __launch_bounds__(256) k_wst(KParams p, int l) {
  __shared__ __align__(16) char smem[SMEM_BYTES]; phase_stats(p, l, smem);
}
__global__ void __launch_bounds__(256) k_wnp(KParams p, int l) {
  __shared__ __align__(16) char smem[SMEM_BYTES]; phase_np(p, l, smem);
}
__global__ void __launch_bounds__(256) k_wpool(KParams p) {
  __shared__ __align__(16) char smem[SMEM_BYTES]; phase_pool(p, smem);
}

extern "C" void kernel_launch(void* const* d_in, const int* in_sizes, int n_in,
                              void* d_out, int out_size, void* d_ws, size_t ws_size,
                              hipStream_t stream) {
  KParams P;
  P.x        = (const float*)d_in[0];
  P.ea       = (const float*)d_in[1];
  P.lin0_w   = (const float*)d_in[2];
  P.lin0_b   = (const float*)d_in[3];
  P.conv_wf  = (const float*)d_in[4];
  P.conv_bf  = (const float*)d_in[5];
  P.conv_ws  = (const float*)d_in[6];
  P.conv_bs  = (const float*)d_in[7];
  P.bn_gamma = (const float*)d_in[8];
  P.bn_beta  = (const float*)d_in[9];
  P.lin1_w   = (const float*)d_in[10];
  P.lin1_b   = (const float*)d_in[11];
  P.fc_w     = (const float*)d_in[12];
  P.fc_b     = (const float*)d_in[13];
  P.lin2_w   = (const float*)d_in[14];
  P.lin2_b   = (const float*)d_in[15];
  P.ei       = (const int*)d_in[16];
  P.batch    = (const int*)d_in[17];
  P.out      = (float*)d_out;

  uintptr_t pp = (uintptr_t)d_ws;
  auto alloc = [&](size_t bytes) {
    pp = (pp + 255) & ~(size_t)255;
    void* r = (void*)pp;
    pp += bytes;
    return r;
  };
  P.h0    = (float*)alloc((size_t)N_NODES * 64 * 4);
  P.h1    = (float*)alloc((size_t)N_NODES * 64 * 4);
  P.projd = (unsigned short*)alloc((size_t)N_NODES * 128 * 2);
  P.projs = (unsigned short*)alloc((size_t)N_NODES * 128 * 2);
  P.aggrA = (float*)alloc((size_t)N_NODES * 64 * 4);
  P.aggrB = (float*)alloc((size_t)N_NODES * 64 * 4);
  P.stat  = (float*)alloc((size_t)NL * 128 * 4);
  P.invc  = (float*)alloc((size_t)N_NODES * 4);
  P.cnt   = (int*)alloc((size_t)N_NODES * 4);
  P.lpre  = (int*)alloc((size_t)N_NODES * 4);
  P.ptot  = (int*)alloc((size_t)SCAN_BLOCKS * 4);
  P.wptr  = (int*)alloc((size_t)N_NODES * 4);
  P.ds2   = (int2*)alloc((size_t)N_EDGES * 8);
  P.grp   = (int*)alloc((size_t)(NG + 1) * 4);
  P.eapb  = (unsigned short*)alloc((size_t)N_EDGES * 64 * 2);
  P.Bp    = (unsigned short*)alloc((size_t)NL * 16 * 64 * 8 * 2);

  hipMemsetAsync(P.cnt, 0, N_NODES * sizeof(int), stream);

  int dev = 0;
  (void)hipGetDevice(&dev);
  int coop = 0;
  (void)hipDeviceGetAttribute(&coop, hipDeviceAttributeCooperativeLaunch, dev);
  if (coop) {
    void* kargs[] = {(void*)&P};
    hipError_t err = hipLaunchCooperativeKernel((const void*)k_mega, dim3(NB), dim3(256),
                                                kargs, 0, stream);
    if (err == hipSuccess) return;
    (void)hipGetLastError();  // clear; fall through to dispatch sequence
  }

  k_w0<<<NB, 256, 0, stream>>>(P);
  k_ws1<<<SCAN_BLOCKS, 256, 0, stream>>>(P);
  k_ws2<<<SCAN_BLOCKS, 256, 0, stream>>>(P);
  k_w3<<<NB, 256, 0, stream>>>(P);
  for (int l = 0; l < NL; ++l) {
    k_we<<<NB, 256, 0, stream>>>(P, l);
    k_wst<<<NB, 256, 0, stream>>>(P, l);
    if (l < NL - 1) k_wnp<<<NB, 256, 0, stream>>>(P, l);
  }
  k_wpool<<<NG, 256, 0, stream>>>(P);
}

// Round 6
// 633.094 us; speedup vs baseline: 3.3407x; 3.3407x over previous
//
#include <hip/hip_runtime.h>
#include <hip/hip_bf16.h>

#define N_NODES 30000
#define N_EDGES 480000
#define NFEAT 92
#define EFEAT 50
#define D1 64
#define ZD 178
#define NL 3
#define NG 256
#define BN_EPS 1e-5f
#define NTILES (N_EDGES / 16)     // 30000 tiles, 1 per wave
#define EDGE_BLOCKS 7500          // logical blocks (4 waves each)
#define EDGE_GRID 7504            // 8 XCDs x 938, guard vbid < 7500

#define LIN0_BLOCKS 512
#define CNT_BLOCKS 1875    // E / 256
#define WPREP_BLOCKS 96    // NL*16*64*8 / 256
#define SCAN_BLOCKS ((N_NODES + 255) / 256)  // 118
#define BUILD_BLOCKS 1875  // E / 256
#define NP_BLOCKS 2048     // nodeproj blocks (R6: 1024->2048, lift 50% occ cap)

typedef __attribute__((ext_vector_type(8))) short bf16x8;
typedef __attribute__((ext_vector_type(8))) unsigned short u16x8;
typedef __attribute__((ext_vector_type(4))) unsigned short u16x4;
typedef __attribute__((ext_vector_type(4))) float f32x4;

static __device__ __forceinline__ unsigned short f2bf(float v) {
  __hip_bfloat16 b = __float2bfloat16(v);
  return *(unsigned short*)&b;
}
static __device__ __forceinline__ float bfu(unsigned short u) {
  union { unsigned int i; float f; } c;
  c.i = ((unsigned int)u) << 16;
  return c.f;
}

// ---------------- shared nodeproj body (used by k_build fused path and k_nodeproj)
// R6: 4-accumulator ILP on the 64-FMA chain (dependent chain 256cy -> ~64cy).
// No register pinning (R2: pinning trades cheap L2 re-gathers for occupancy loss).
static __device__ __forceinline__ void nodeproj_body(
    int blk0, int nblk, const float* __restrict__ hin, float* __restrict__ hout,
    const float* __restrict__ wfp, const float* __restrict__ wsm,
    unsigned short* __restrict__ projd_pk, unsigned short* __restrict__ projs_pk,
    const float* __restrict__ aggr, float* __restrict__ aggr_z,
    const float* __restrict__ invc, const float* __restrict__ musum,
    const float* __restrict__ sqsum, const float* __restrict__ gamma,
    const float* __restrict__ beta, int do_bn, float (*hl)[64]) {
  const int lane = threadIdx.x & 63;
  const int w = threadIdx.x >> 6;  // 0..3
  const float* W = (w < 2) ? wfp : wsm;
  const int roff = (w & 1) * 64;  // 0=dst rows, 1=src rows
  float wreg[D1];
#pragma unroll
  for (int k = 0; k < D1; ++k) wreg[k] = W[(size_t)(roff + k) * D1 + lane];
  unsigned short* pk = (w & 1) ? projs_pk : projd_pk;
  const int slot = (w < 2) ? 0 : 4;  // Wf -> lo4, Ws -> hi4
  const int poff = (lane >> 2) * 8 + (lane & 3) + slot;
  float r = 0.0f, sh = 0.0f;
  if (do_bn) {
    const float mu = musum[lane] * (1.0f / N_NODES);
    const float var = sqsum[lane] * (1.0f / N_NODES) - mu * mu;
    r = gamma[lane] * rsqrtf(var + BN_EPS);
    sh = beta[lane] - mu * r;
  }
  for (int i = blk0; i < N_NODES; i += nblk) {
    float hv = hin[(size_t)i * D1 + lane];
    if (do_bn) {
      const float av = aggr[(size_t)i * D1 + lane] * invc[i];
      hv = fmaxf(hv + fmaf(av, r, sh), 0.0f);
      if (w == 0) hout[(size_t)i * D1 + lane] = hv;
    }
    if (w == 1) aggr_z[(size_t)i * D1 + lane] = 0.0f;  // zero for next edgemm
    hl[w][lane] = hv;
    __builtin_amdgcn_wave_barrier();
    const float4* hr = (const float4*)&hl[w][0];
    float a0 = 0.0f, a1 = 0.0f, a2 = 0.0f, a3 = 0.0f;
#pragma unroll
    for (int q = 0; q < 4; ++q) {
      const float4 v0 = hr[q * 4 + 0];
      const float4 v1 = hr[q * 4 + 1];
      const float4 v2 = hr[q * 4 + 2];
      const float4 v3 = hr[q * 4 + 3];
      a0 = fmaf(v0.x, wreg[q * 16 + 0], a0);
      a0 = fmaf(v0.y, wreg[q * 16 + 1], a0);
      a0 = fmaf(v0.z, wreg[q * 16 + 2], a0);
      a0 = fmaf(v0.w, wreg[q * 16 + 3], a0);
      a1 = fmaf(v1.x, wreg[q * 16 + 4], a1);
      a1 = fmaf(v1.y, wreg[q * 16 + 5], a1);
      a1 = fmaf(v1.z, wreg[q * 16 + 6], a1);
      a1 = fmaf(v1.w, wreg[q * 16 + 7], a1);
      a2 = fmaf(v2.x, wreg[q * 16 + 8], a2);
      a2 = fmaf(v2.y, wreg[q * 16 + 9], a2);
      a2 = fmaf(v2.z, wreg[q * 16 + 10], a2);
      a2 = fmaf(v2.w, wreg[q * 16 + 11], a2);
      a3 = fmaf(v3.x, wreg[q * 16 + 12], a3);
      a3 = fmaf(v3.y, wreg[q * 16 + 13], a3);
      a3 = fmaf(v3.z, wreg[q * 16 + 14], a3);
      a3 = fmaf(v3.w, wreg[q * 16 + 15], a3);
    }
    pk[(size_t)i * 128 + poff] = f2bf((a0 + a1) + (a2 + a3));
    __builtin_amdgcn_wave_barrier();
  }
}

// ---------------- init: lin0 + dst counts + B fragments (block-range split) --
extern "C" __global__ void __launch_bounds__(256)
k_init(const float* __restrict__ x, const float* __restrict__ w,
       const float* __restrict__ b, float* __restrict__ h,
       const int* __restrict__ ei, int* __restrict__ cnt,
       const float* __restrict__ conv_wf, const float* __restrict__ conv_ws,
       unsigned short* __restrict__ Bp) {
  const int blk = blockIdx.x;
  if (blk < LIN0_BLOCKS) {
    const int lane = threadIdx.x & 63;
    const int wave = (blk * 256 + threadIdx.x) >> 6;
    const int nw = (LIN0_BLOCKS * 256) >> 6;
    float wreg[NFEAT];
#pragma unroll
    for (int k = 0; k < NFEAT; ++k) wreg[k] = w[k * D1 + lane];
    const float bj = b[lane];
    for (int i = wave; i < N_NODES; i += nw) {
      const float2* xr = (const float2*)(x + (size_t)i * NFEAT);
      float acc = bj;
#pragma unroll
      for (int k = 0; k < NFEAT / 2; ++k) {
        const float2 v = xr[k];
        acc = fmaf(v.x, wreg[2 * k], acc);
        acc = fmaf(v.y, wreg[2 * k + 1], acc);
      }
      h[(size_t)i * D1 + lane] = fmaxf(acc, 0.0f);
    }
  } else if (blk < LIN0_BLOCKS + CNT_BLOCKS) {
    const int e = (blk - LIN0_BLOCKS) * 256 + threadIdx.x;
    if (e < N_EDGES) atomicAdd(&cnt[ei[N_EDGES + e]], 1);
  } else {
    const int idx = (blk - LIN0_BLOCKS - CNT_BLOCKS) * 256 + threadIdx.x;
    const int j = idx & 7;
    const int lane = (idx >> 3) & 63;
    const int frag = (idx >> 9) & 15;  // (m*2+t)*4+n
    const int l = idx >> 13;
    const int n = frag & 3;
    const int t = (frag >> 2) & 1;
    const int m = frag >> 3;
    const int k = t * 32 + (lane >> 4) * 8 + j;
    const int feat = (lane & 15) * 4 + n;
    float v = 0.0f;
    if (k < EFEAT) {
      const float* W = (m == 0) ? conv_wf : conv_ws;
      v = W[(size_t)l * ZD * D1 + (size_t)(128 + k) * D1 + feat];
    }
    Bp[idx] = f2bf(v);
  }
}

// ---------------- scan phase 1: per-block partial sums ----------------
extern "C" __global__ void __launch_bounds__(256)
k_scan1(const int* __restrict__ cnt, int* __restrict__ lpre, int* __restrict__ ptot) {
  const int t = threadIdx.x;
  const int idx = blockIdx.x * 256 + t;
  const int v = (idx < N_NODES) ? cnt[idx] : 0;
  __shared__ int bs[256];
  bs[t] = v;
  __syncthreads();
  for (int off = 1; off < 256; off <<= 1) {
    int u = (t >= off) ? bs[t - off] : 0;
    __syncthreads();
    bs[t] += u;
    __syncthreads();
  }
  if (idx < N_NODES) lpre[idx] = bs[t] - v;
  if (t == 255) ptot[blockIdx.x] = bs[255];
}

// scan phase 2+3: redundant block-offset scan + wptr/invc/grp
extern "C" __global__ void __launch_bounds__(256)
k_scan23(const int* __restrict__ cnt, const int* __restrict__ lpre,
         const int* __restrict__ ptot, const int* __restrict__ batch,
         int* __restrict__ wptr, float* __restrict__ invc,
         int* __restrict__ grp) {
  __shared__ int bs[128];
  const int t = threadIdx.x;
  if (t < 128) bs[t] = (t < SCAN_BLOCKS) ? ptot[t] : 0;
  __syncthreads();
  for (int off = 1; off < 128; off <<= 1) {
    int u = 0;
    if (t < 128 && t >= off) u = bs[t - off];
    __syncthreads();
    if (t < 128 && t >= off) bs[t] += u;
    __syncthreads();
  }
  const int idx = blockIdx.x * 256 + t;
  if (idx >= N_NODES) return;
  const int bid = idx >> 8;
  const int boff = (bid == 0) ? 0 : bs[bid - 1];
  wptr[idx] = boff + lpre[idx];
  invc[idx] = 1.0f / fmaxf((float)cnt[idx], 1.0f);
  const int bt = batch[idx];
  if (idx == 0)
    for (int g = 0; g <= bt; ++g) grp[g] = 0;
  else {
    const int pb = batch[idx - 1];
    for (int g = pb + 1; g <= bt; ++g) grp[g] = idx;
  }
  if (idx == N_NODES - 1)
    for (int g = bt + 1; g <= NG; ++g) grp[g] = N_NODES;
}

// ---------------- build: CSR scatter (int2 dst,src) + bf16 pack + nodeproj0 --
// blocks [0, BUILD_BLOCKS): scatter+pack; [BUILD_BLOCKS, +NP_BLOCKS): nodeproj l=0.
// (R1-R5 lesson: every un-fusing of this kernel lost time — the 480k returned
//  atomics are pure latency and only cost ~0 when buried under streaming work.)
extern "C" __global__ void __launch_bounds__(256)
k_build(const int* __restrict__ ei, int* __restrict__ wptr,
        int2* __restrict__ ds2, const float* __restrict__ ea,
        unsigned short* __restrict__ eapb,
        const float* __restrict__ h0, const float* __restrict__ wfl,
        const float* __restrict__ wsl, unsigned short* __restrict__ projd_pk,
        unsigned short* __restrict__ projs_pk, float* __restrict__ aggrA) {
  __shared__ __align__(16) int lpos[256];
  if (blockIdx.x >= BUILD_BLOCKS) {
    nodeproj_body(blockIdx.x - BUILD_BLOCKS, NP_BLOCKS, h0, nullptr, wfl, wsl,
                  projd_pk, projs_pk, nullptr, aggrA, nullptr, nullptr, nullptr,
                  nullptr, nullptr, 0, (float(*)[64])lpos);
    return;
  }
  const int e0 = blockIdx.x * 256;
  {
    const int e = e0 + threadIdx.x;
    const int d = ei[N_EDGES + e];
    const int pos = atomicAdd(&wptr[d], 1);
    ds2[pos] = make_int2(d, ei[e]);  // one 8B scatter (half the sectors)
    lpos[threadIdx.x] = pos;
  }
  __syncthreads();
  const int l16 = threadIdx.x & 15;
  const int sub = threadIdx.x >> 4;  // 0..15
#pragma unroll
  for (int r = 0; r < 16; ++r) {
    const int eb = r * 16 + sub;
    const size_t ge = e0 + eb;
    const int pos = lpos[eb];
    unsigned short o0 = 0, o1 = 0, o2 = 0, o3 = 0;
    if (l16 < 12) {
      const float4 v = *(const float4*)(ea + ge * EFEAT + l16 * 4);
      o0 = f2bf(v.x); o1 = f2bf(v.y); o2 = f2bf(v.z); o3 = f2bf(v.w);
    } else if (l16 == 12) {
      const float2 v = *(const float2*)(ea + ge * EFEAT + 48);
      o0 = f2bf(v.x); o1 = f2bf(v.y);
    }
    u16x4 st;
    st[0] = o0; st[1] = o1; st[2] = o2; st[3] = o3;
    *(u16x4*)(eapb + ((size_t)pos << 6) + l16 * 4) = st;
  }
}

// ---------------- standalone node projections (layers 1,2) ----------------
extern "C" __global__ void __launch_bounds__(256)
k_nodeproj(const float* __restrict__ hin, float* __restrict__ hout,
           const float* __restrict__ wfp, const float* __restrict__ wsm,
           unsigned short* __restrict__ projd_pk, unsigned short* __restrict__ projs_pk,
           const float* __restrict__ aggr, float* __restrict__ aggr_z,
           const float* __restrict__ invc,
           const float* __restrict__ musum, const float* __restrict__ sqsum,
           const float* __restrict__ gamma, const float* __restrict__ beta) {
  __shared__ float hl[4][64];
  nodeproj_body(blockIdx.x, gridDim.x, hin, hout, wfp, wsm, projd_pk, projs_pk,
                aggr, aggr_z, invc, musum, sqsum, gamma, beta, 1, hl);
}

// ---------------- MFMA edge kernel: 4 waves/block, 1 tile per wave ----------
// XCD-aware swizzle; (dst,src) packed int2. (R4: multi-tile variant regressed —
// 30k short waves beat 7.5k long ones; keep 1 tile/wave.)
extern "C" __global__ void __launch_bounds__(256)
k_edgemm(const unsigned short* __restrict__ projd_pk,
         const unsigned short* __restrict__ projs_pk,
         const unsigned short* __restrict__ eapb,
         const int2* __restrict__ ds2,
         const unsigned short* __restrict__ Bp,
         const float* __restrict__ bfp, const float* __restrict__ bsp,
         float* __restrict__ aggr, float* __restrict__ musum,
         float* __restrict__ sqsum) {
  const int lane = threadIdx.x & 63;
  const int wv = threadIdx.x >> 6;
  const int col = lane & 15;
  const int quad = lane >> 4;
  __shared__ float mlds[4][16][68];

  const int vbid = (blockIdx.x & 7) * 938 + (blockIdx.x >> 3);
  if (blockIdx.x == 0 && wv == 0) {  // zero stats accumulators for k_stats
    musum[lane] = 0.0f;
    sqsum[lane] = 0.0f;
  }
  if (vbid >= EDGE_BLOCKS) return;

  const int t = vbid * 4 + wv;  // tile id; exactly NTILES waves
  const int base = t * 16;

  // independent streamed loads — all in flight together
  const int4 p01 = *(const int4*)(ds2 + base + quad * 4);      // edges r=0,1
  const int4 p23 = *(const int4*)(ds2 + base + quad * 4 + 2);  // edges r=2,3
  const int dr[4] = {p01.x, p01.z, p23.x, p23.z};
  const int sr[4] = {p01.y, p01.w, p23.y, p23.w};
  const bf16x8 Af0 = *(const bf16x8*)(eapb + ((size_t)(base + col) << 6) + quad * 8);
  const bf16x8 Af1 = *(const bf16x8*)(eapb + ((size_t)(base + col) << 6) + 32 + quad * 8);

  bf16x8 Bf[2][2][4];
#pragma unroll
  for (int m = 0; m < 2; ++m)
#pragma unroll
    for (int tt = 0; tt < 2; ++tt)
#pragma unroll
      for (int n = 0; n < 4; ++n)
        Bf[m][tt][n] = *(const bf16x8*)(Bp + ((((m * 2 + tt) * 4 + n) * 64 + lane) * 8));

  const f32x4 bf4 = *(const f32x4*)(bfp + col * 4);
  const f32x4 bs4 = *(const f32x4*)(bsp + col * 4);

  // C init from packed bf16 projections: 2 gathered 16B loads per edge row
  f32x4 aF[4], aS[4];
#pragma unroll
  for (int r = 0; r < 4; ++r) {
    const int d = dr[r];
    const int s = sr[r];
    const u16x8 pd = *(const u16x8*)(projd_pk + (size_t)d * 128 + col * 8);
    const u16x8 ss = *(const u16x8*)(projs_pk + (size_t)s * 128 + col * 8);
#pragma unroll
    for (int n = 0; n < 4; ++n) {
      aF[n][r] = bfu(pd[n]) + bfu(ss[n]) + bf4[n];
      aS[n][r] = bfu(pd[n + 4]) + bfu(ss[n + 4]) + bs4[n];
    }
  }

#pragma unroll
  for (int n = 0; n < 4; ++n) {
    aF[n] = __builtin_amdgcn_mfma_f32_16x16x32_bf16(Af0, Bf[0][0][n], aF[n], 0, 0, 0);
    aF[n] = __builtin_amdgcn_mfma_f32_16x16x32_bf16(Af1, Bf[0][1][n], aF[n], 0, 0, 0);
    aS[n] = __builtin_amdgcn_mfma_f32_16x16x32_bf16(Af0, Bf[1][0][n], aS[n], 0, 0, 0);
    aS[n] = __builtin_amdgcn_mfma_f32_16x16x32_bf16(Af1, Bf[1][1][n], aS[n], 0, 0, 0);
  }

  // epilogue: m = sigmoid(af) * softplus(as) -> LDS tile
#pragma unroll
  for (int r = 0; r < 4; ++r) {
    f32x4 mv;
#pragma unroll
    for (int n = 0; n < 4; ++n) {
      const float af = aF[n][r];
      const float as = aS[n][r];
      const float sg = __builtin_amdgcn_rcpf(1.0f + __expf(-af));
      const float sp = fmaxf(as, 0.0f) + __logf(1.0f + __expf(-fabsf(as)));
      mv[n] = sg * sp;
    }
    *(f32x4*)&mlds[wv][quad * 4 + r][col * 4] = mv;
  }
  __builtin_amdgcn_wave_barrier();

  // segmented reduce over the 16 dst-sorted CSR rows (raw sums; mean later)
  float sum = 0.0f;
  int dcur = ds2[base].x;
#pragma unroll
  for (int p = 0; p < 16; ++p) {
    sum += mlds[wv][p][lane];
    const int dnxt = (p < 15) ? ds2[base + p + 1].x : -1;
    if (dnxt != dcur) {
      atomicAdd(&aggr[(size_t)dcur * D1 + lane], sum);
      sum = 0.0f;
      dcur = dnxt;
    }
  }
}

// ---------------- BN stats over aggr*invc ----------------
extern "C" __global__ void __launch_bounds__(256)
k_stats(const float* __restrict__ aggr, const float* __restrict__ invc,
        float* __restrict__ musum, float* __restrict__ sqsum) {
  const int j = threadIdx.x & 63;
  const int rid = (blockIdx.x * blockDim.x + threadIdx.x) >> 6;
  const int rstr = (gridDim.x * blockDim.x) >> 6;
  float s = 0.0f, sq = 0.0f;
  for (int i = rid; i < N_NODES; i += rstr) {
    const float v = aggr[(size_t)i * D1 + j] * invc[i];
    s += v;
    sq = fmaf(v, v, sq);
  }
  __shared__ float ls[256], lq[256];
  ls[threadIdx.x] = s;
  lq[threadIdx.x] = sq;
  __syncthreads();
  if (threadIdx.x < 64) {
    s = ls[j] + ls[64 + j] + ls[128 + j] + ls[192 + j];
    sq = lq[j] + lq[64 + j] + lq[128 + j] + lq[192 + j];
    atomicAdd(&musum[j], s);
    atomicAdd(&sqsum[j], sq);
  }
}

// ---------------- fused pool (final BN update) + MLP chain ------------------
extern "C" __global__ void __launch_bounds__(256)
k_poolmlp(const float* __restrict__ h, const float* __restrict__ aggr,
          const float* __restrict__ invc,
          const float* __restrict__ musum, const float* __restrict__ sqsum,
          const float* __restrict__ gamma, const float* __restrict__ beta,
          const int* __restrict__ grp,
          const float* __restrict__ lin1_w, const float* __restrict__ lin1_b,
          const float* __restrict__ fc_w, const float* __restrict__ fc_b,
          const float* __restrict__ lin2_w, const float* __restrict__ lin2_b,
          float* __restrict__ out) {
  const int g = blockIdx.x;
  const int lane = threadIdx.x & 63;
  const int wv = threadIdx.x >> 6;
  const float mu = musum[lane] * (1.0f / N_NODES);
  const float var = sqsum[lane] * (1.0f / N_NODES) - mu * mu;
  const float r = gamma[lane] * rsqrtf(var + BN_EPS);
  const float sh = beta[lane] - mu * r;
  const int s = grp[g], e = grp[g + 1];
  float acc = 0.0f;
  for (int i = s + wv; i < e; i += 4) {
    const float hv = h[(size_t)i * D1 + lane];
    const float av = aggr[(size_t)i * D1 + lane] * invc[i];
    acc += fmaxf(hv + fmaf(av, r, sh), 0.0f);
  }
  __shared__ float red[4][64];
  __shared__ float vin[64];
  red[wv][lane] = acc;
  __syncthreads();
  const int j = threadIdx.x;
  float v = 0.0f;
  if (j < 64) {
    const float inv = 1.0f / fmaxf((float)(e - s), 1.0f);
    v = (red[0][j] + red[1][j] + red[2][j] + red[3][j]) * inv;
  }
  for (int layer = 0; layer < 3; ++layer) {
    if (j < 64) vin[j] = v;
    __syncthreads();
    if (j < 64) {
      const float* W;
      const float* B;
      if (layer == 0) {
        W = lin1_w;
        B = lin1_b;
      } else {
        W = fc_w + (size_t)(layer - 1) * D1 * D1;
        B = fc_b + (size_t)(layer - 1) * D1;
      }
      float a2 = B[j];
#pragma unroll 16
      for (int k = 0; k < D1; ++k) a2 = fmaf(vin[k], W[k * D1 + j], a2);
      v = fmaxf(a2, 0.0f);
    }
    __syncthreads();
  }
  if (j < 64) {
    float p = v * lin2_w[j];
#pragma unroll
    for (int off = 32; off > 0; off >>= 1) p += __shfl_down(p, off);
    if (j == 0) out[g] = p + lin2_b[0];
  }
}

extern "C" void kernel_launch(void* const* d_in, const int* in_sizes, int n_in,
                              void* d_out, int out_size, void* d_ws, size_t ws_size,
                              hipStream_t stream) {
  const float* x        = (const float*)d_in[0];
  const float* ea       = (const float*)d_in[1];
  const float* lin0_w   = (const float*)d_in[2];
  const float* lin0_b   = (const float*)d_in[3];
  const float* conv_wf  = (const float*)d_in[4];
  const float* conv_bf  = (const float*)d_in[5];
  const float* conv_ws  = (const float*)d_in[6];
  const float* conv_bs  = (const float*)d_in[7];
  const float* bn_gamma = (const float*)d_in[8];
  const float* bn_beta  = (const float*)d_in[9];
  const float* lin1_w   = (const float*)d_in[10];
  const float* lin1_b   = (const float*)d_in[11];
  const float* fc_w     = (const float*)d_in[12];
  const float* fc_b     = (const float*)d_in[13];
  const float* lin2_w   = (const float*)d_in[14];
  const float* lin2_b   = (const float*)d_in[15];
  const int*   ei       = (const int*)d_in[16];
  const int*   batch    = (const int*)d_in[17];

  uintptr_t p = (uintptr_t)d_ws;
  auto alloc = [&](size_t bytes) {
    p = (p + 255) & ~(size_t)255;
    void* r = (void*)p;
    p += bytes;
    return r;
  };
  float* h0     = (float*)alloc((size_t)N_NODES * 64 * 4);
  float* h1     = (float*)alloc((size_t)N_NODES * 64 * 4);
  unsigned short* projd_pk = (unsigned short*)alloc((size_t)N_NODES * 128 * 2);
  unsigned short* projs_pk = (unsigned short*)alloc((size_t)N_NODES * 128 * 2);
  float* aggrA  = (float*)alloc((size_t)N_NODES * 64 * 4);
  float* aggrB  = (float*)alloc((size_t)N_NODES * 64 * 4);
  float* musum  = (float*)alloc(128 * 4);
  float* sqsum  = musum + 64;
  float* invc   = (float*)alloc((size_t)N_NODES * 4);
  int*   cnt    = (int*)alloc((size_t)N_NODES * 4);
  int*   lpre   = (int*)alloc((size_t)N_NODES * 4);
  int*   ptot   = (int*)alloc((size_t)SCAN_BLOCKS * 4);
  int*   wptr   = (int*)alloc((size_t)N_NODES * 4);
  int2*  ds2    = (int2*)alloc((size_t)N_EDGES * 8);
  int*   grp    = (int*)alloc((size_t)(NG + 1) * 4);
  unsigned short* eapb = (unsigned short*)alloc((size_t)N_EDGES * 64 * 2);
  unsigned short* Bp   = (unsigned short*)alloc((size_t)NL * 16 * 64 * 8 * 2);

  hipMemsetAsync(cnt, 0, N_NODES * sizeof(int), stream);
  k_init<<<LIN0_BLOCKS + CNT_BLOCKS + WPREP_BLOCKS, 256, 0, stream>>>(
      x, lin0_w, lin0_b, h0, ei, cnt, conv_wf, conv_ws, Bp);
  k_scan1<<<SCAN_BLOCKS, 256, 0, stream>>>(cnt, lpre, ptot);
  k_scan23<<<SCAN_BLOCKS, 256, 0, stream>>>(cnt, lpre, ptot, batch, wptr, invc, grp);
  // fused: CSR build + bf16 pack + nodeproj(l=0)
  k_build<<<BUILD_BLOCKS + NP_BLOCKS, 256, 0, stream>>>(
      ei, wptr, ds2, ea, eapb, h0, conv_wf, conv_ws, projd_pk, projs_pk, aggrA);

  float* aggr_of[NL] = {aggrA, aggrB, aggrA};
  const float* hin_of[NL]  = {h0, h0, h1};
  float* hout_of[NL]       = {h0, h1, h0};

  for (int l = 0; l < NL; ++l) {
    const float* wfl = conv_wf + (size_t)l * ZD * D1;
    const float* wsl = conv_ws + (size_t)l * ZD * D1;
    if (l > 0)
      k_nodeproj<<<NP_BLOCKS, 256, 0, stream>>>(
          hin_of[l], hout_of[l], wfl, wsl, projd_pk, projs_pk,
          aggr_of[l - 1], aggr_of[l], invc, musum, sqsum,
          bn_gamma + (size_t)(l - 1) * D1, bn_beta + (size_t)(l - 1) * D1);
    k_edgemm<<<EDGE_GRID, 256, 0, stream>>>(
        projd_pk, projs_pk, eapb, ds2,
        Bp + (size_t)l * 16 * 64 * 8,
        conv_bf + (size_t)l * D1, conv_bs + (size_t)l * D1,
        aggr_of[l], musum, sqsum);
    k_stats<<<256, 256, 0, stream>>>(aggr_of[l], invc, musum, sqsum);
  }

  k_poolmlp<<<NG, 256, 0, stream>>>(h0, aggr_of[2], invc, musum, sqsum,
                                    bn_gamma + (size_t)2 * D1, bn_beta + (size_t)2 * D1,
                                    grp, lin1_w, lin1_b, fc_w, fc_b,
                                    lin2_w, lin2_b, (float*)d_out);
}

// Round 8
// 594.444 us; speedup vs baseline: 3.5579x; 1.0650x over previous
//
#include <hip/hip_runtime.h>
#include <hip/hip_bf16.h>

#define N_NODES 30000
#define N_EDGES 480000
#define NFEAT 92
#define EFEAT 50
#define D1 64
#define ZD 178
#define NL 3
#define NG 256
#define BN_EPS 1e-5f
#define NTILES (N_EDGES / 16)     // 30000 tiles, 1 per wave
#define EDGE_BLOCKS 7500          // logical blocks (4 waves each)
#define EDGE_GRID 7504            // 8 XCDs x 938, guard vbid < 7500

#define LIN0_BLOCKS 512
#define CNT_BLOCKS 1875    // E / 256
#define WPREP_BLOCKS 96    // NL*16*64*8 / 256
#define SCAN_BLOCKS ((N_NODES + 255) / 256)  // 118
#define BUILD_BLOCKS 1875  // E / 256
#define NP_BLOCKS 1024     // nodeproj blocks fused into k_build (baseline value)
#define NPM_BLOCKS 1875    // MFMA nodeproj: N_NODES/16 tiles, 1 per block

typedef __attribute__((ext_vector_type(8))) short bf16x8;
typedef __attribute__((ext_vector_type(8))) unsigned short u16x8;
typedef __attribute__((ext_vector_type(4))) unsigned short u16x4;
typedef __attribute__((ext_vector_type(4))) float f32x4;

static __device__ __forceinline__ unsigned short f2bf(float v) {
  __hip_bfloat16 b = __float2bfloat16(v);
  return *(unsigned short*)&b;
}
static __device__ __forceinline__ float bfu(unsigned short u) {
  union { unsigned int i; float f; } c;
  c.i = ((unsigned int)u) << 16;
  return c.f;
}

// ---------------- baseline scalar nodeproj body (still used by k_build np0 tail)
static __device__ __forceinline__ void nodeproj_body(
    int blk0, int nblk, const float* __restrict__ hin, float* __restrict__ hout,
    const float* __restrict__ wfp, const float* __restrict__ wsm,
    unsigned short* __restrict__ projd_pk, unsigned short* __restrict__ projs_pk,
    const float* __restrict__ aggr, float* __restrict__ aggr_z,
    const float* __restrict__ invc, const float* __restrict__ musum,
    const float* __restrict__ sqsum, const float* __restrict__ gamma,
    const float* __restrict__ beta, int do_bn, float (*hl)[64]) {
  const int lane = threadIdx.x & 63;
  const int w = threadIdx.x >> 6;  // 0..3
  const float* W = (w < 2) ? wfp : wsm;
  const int roff = (w & 1) * 64;  // 0=dst rows, 1=src rows
  float wreg[D1];
#pragma unroll
  for (int k = 0; k < D1; ++k) wreg[k] = W[(size_t)(roff + k) * D1 + lane];
  unsigned short* pk = (w & 1) ? projs_pk : projd_pk;
  const int slot = (w < 2) ? 0 : 4;  // Wf -> lo4, Ws -> hi4
  const int poff = (lane >> 2) * 8 + (lane & 3) + slot;
  float r = 0.0f, sh = 0.0f;
  if (do_bn) {
    const float mu = musum[lane] * (1.0f / N_NODES);
    const float var = sqsum[lane] * (1.0f / N_NODES) - mu * mu;
    r = gamma[lane] * rsqrtf(var + BN_EPS);
    sh = beta[lane] - mu * r;
  }
  for (int i = blk0; i < N_NODES; i += nblk) {
    float hv = hin[(size_t)i * D1 + lane];
    if (do_bn) {
      const float av = aggr[(size_t)i * D1 + lane] * invc[i];
      hv = fmaxf(hv + fmaf(av, r, sh), 0.0f);
      if (w == 0) hout[(size_t)i * D1 + lane] = hv;
    }
    if (w == 1) aggr_z[(size_t)i * D1 + lane] = 0.0f;  // zero for next edgemm
    hl[w][lane] = hv;
    __builtin_amdgcn_wave_barrier();
    const float4* hr = (const float4*)&hl[w][0];
    float acc = 0.0f;
#pragma unroll
    for (int k4 = 0; k4 < D1 / 4; ++k4) {
      const float4 v = hr[k4];
      acc = fmaf(v.x, wreg[4 * k4 + 0], acc);
      acc = fmaf(v.y, wreg[4 * k4 + 1], acc);
      acc = fmaf(v.z, wreg[4 * k4 + 2], acc);
      acc = fmaf(v.w, wreg[4 * k4 + 3], acc);
    }
    pk[(size_t)i * 128 + poff] = f2bf(acc);
    __builtin_amdgcn_wave_barrier();
  }
}

// ---------------- init: lin0 + dst counts + B fragments (block-range split) --
extern "C" __global__ void __launch_bounds__(256)
k_init(const float* __restrict__ x, const float* __restrict__ w,
       const float* __restrict__ b, float* __restrict__ h,
       const int* __restrict__ ei, int* __restrict__ cnt,
       const float* __restrict__ conv_wf, const float* __restrict__ conv_ws,
       unsigned short* __restrict__ Bp) {
  const int blk = blockIdx.x;
  if (blk < LIN0_BLOCKS) {
    const int lane = threadIdx.x & 63;
    const int wave = (blk * 256 + threadIdx.x) >> 6;
    const int nw = (LIN0_BLOCKS * 256) >> 6;
    float wreg[NFEAT];
#pragma unroll
    for (int k = 0; k < NFEAT; ++k) wreg[k] = w[k * D1 + lane];
    const float bj = b[lane];
    for (int i = wave; i < N_NODES; i += nw) {
      const float2* xr = (const float2*)(x + (size_t)i * NFEAT);
      float acc = bj;
#pragma unroll
      for (int k = 0; k < NFEAT / 2; ++k) {
        const float2 v = xr[k];
        acc = fmaf(v.x, wreg[2 * k], acc);
        acc = fmaf(v.y, wreg[2 * k + 1], acc);
      }
      h[(size_t)i * D1 + lane] = fmaxf(acc, 0.0f);
    }
  } else if (blk < LIN0_BLOCKS + CNT_BLOCKS) {
    const int e = (blk - LIN0_BLOCKS) * 256 + threadIdx.x;
    if (e < N_EDGES) atomicAdd(&cnt[ei[N_EDGES + e]], 1);
  } else {
    const int idx = (blk - LIN0_BLOCKS - CNT_BLOCKS) * 256 + threadIdx.x;
    const int j = idx & 7;
    const int lane = (idx >> 3) & 63;
    const int frag = (idx >> 9) & 15;  // (m*2+t)*4+n
    const int l = idx >> 13;
    const int n = frag & 3;
    const int t = (frag >> 2) & 1;
    const int m = frag >> 3;
    const int k = t * 32 + (lane >> 4) * 8 + j;
    const int feat = (lane & 15) * 4 + n;
    float v = 0.0f;
    if (k < EFEAT) {
      const float* W = (m == 0) ? conv_wf : conv_ws;
      v = W[(size_t)l * ZD * D1 + (size_t)(128 + k) * D1 + feat];
    }
    Bp[idx] = f2bf(v);
  }
}

// ---------------- scan phase 1: per-block partial sums ----------------
extern "C" __global__ void __launch_bounds__(256)
k_scan1(const int* __restrict__ cnt, int* __restrict__ lpre, int* __restrict__ ptot) {
  const int t = threadIdx.x;
  const int idx = blockIdx.x * 256 + t;
  const int v = (idx < N_NODES) ? cnt[idx] : 0;
  __shared__ int bs[256];
  bs[t] = v;
  __syncthreads();
  for (int off = 1; off < 256; off <<= 1) {
    int u = (t >= off) ? bs[t - off] : 0;
    __syncthreads();
    bs[t] += u;
    __syncthreads();
  }
  if (idx < N_NODES) lpre[idx] = bs[t] - v;
  if (t == 255) ptot[blockIdx.x] = bs[255];
}

// scan phase 2+3: redundant block-offset scan + wptr/invc/grp
extern "C" __global__ void __launch_bounds__(256)
k_scan23(const int* __restrict__ cnt, const int* __restrict__ lpre,
         const int* __restrict__ ptot, const int* __restrict__ batch,
         int* __restrict__ wptr, float* __restrict__ invc,
         int* __restrict__ grp) {
  __shared__ int bs[128];
  const int t = threadIdx.x;
  if (t < 128) bs[t] = (t < SCAN_BLOCKS) ? ptot[t] : 0;
  __syncthreads();
  for (int off = 1; off < 128; off <<= 1) {
    int u = 0;
    if (t < 128 && t >= off) u = bs[t - off];
    __syncthreads();
    if (t < 128 && t >= off) bs[t] += u;
    __syncthreads();
  }
  const int idx = blockIdx.x * 256 + t;
  if (idx >= N_NODES) return;
  const int bid = idx >> 8;
  const int boff = (bid == 0) ? 0 : bs[bid - 1];
  wptr[idx] = boff + lpre[idx];
  invc[idx] = 1.0f / fmaxf((float)cnt[idx], 1.0f);
  const int bt = batch[idx];
  if (idx == 0)
    for (int g = 0; g <= bt; ++g) grp[g] = 0;
  else {
    const int pb = batch[idx - 1];
    for (int g = pb + 1; g <= bt; ++g) grp[g] = idx;
  }
  if (idx == N_NODES - 1)
    for (int g = bt + 1; g <= NG; ++g) grp[g] = N_NODES;
}

// ---------------- build: CSR scatter (int2 dst,src) + bf16 pack + nodeproj0 --
// blocks [0, BUILD_BLOCKS): scatter+pack; [BUILD_BLOCKS, +NP_BLOCKS): nodeproj l=0.
extern "C" __global__ void __launch_bounds__(256)
k_build(const int* __restrict__ ei, int* __restrict__ wptr,
        int2* __restrict__ ds2, const float* __restrict__ ea,
        unsigned short* __restrict__ eapb,
        const float* __restrict__ h0, const float* __restrict__ wfl,
        const float* __restrict__ wsl, unsigned short* __restrict__ projd_pk,
        unsigned short* __restrict__ projs_pk, float* __restrict__ aggrA) {
  __shared__ __align__(16) int lpos[256];
  if (blockIdx.x >= BUILD_BLOCKS) {
    nodeproj_body(blockIdx.x - BUILD_BLOCKS, NP_BLOCKS, h0, nullptr, wfl, wsl,
                  projd_pk, projs_pk, nullptr, aggrA, nullptr, nullptr, nullptr,
                  nullptr, nullptr, 0, (float(*)[64])lpos);
    return;
  }
  const int e0 = blockIdx.x * 256;
  {
    const int e = e0 + threadIdx.x;
    const int d = ei[N_EDGES + e];
    const int pos = atomicAdd(&wptr[d], 1);
    ds2[pos] = make_int2(d, ei[e]);  // one 8B scatter (half the sectors)
    lpos[threadIdx.x] = pos;
  }
  __syncthreads();
  const int l16 = threadIdx.x & 15;
  const int sub = threadIdx.x >> 4;  // 0..15
#pragma unroll
  for (int r = 0; r < 16; ++r) {
    const int eb = r * 16 + sub;
    const size_t ge = e0 + eb;
    const int pos = lpos[eb];
    unsigned short o0 = 0, o1 = 0, o2 = 0, o3 = 0;
    if (l16 < 12) {
      const float4 v = *(const float4*)(ea + ge * EFEAT + l16 * 4);
      o0 = f2bf(v.x); o1 = f2bf(v.y); o2 = f2bf(v.z); o3 = f2bf(v.w);
    } else if (l16 == 12) {
      const float2 v = *(const float2*)(ea + ge * EFEAT + 48);
      o0 = f2bf(v.x); o1 = f2bf(v.y);
    }
    u16x4 st;
    st[0] = o0; st[1] = o1; st[2] = o2; st[3] = o3;
    *(u16x4*)(eapb + ((size_t)pos << 6) + l16 * 4) = st;
  }
}

// ---------------- R7: MFMA node projection (layers 1,2) ----------------
// One 16-node tile per block. Stage 1: elementwise BN/residual/relu -> LDS
// (identical side effects: hout write, aggr_z zero). Stage 2: each wave owns
// one combo (Wf/Ws x dst/src) and computes [16 nodes x 64 feats] via
// 4 feature-tiles x 2 K-slice MFMAs, storing bf16 into the packed pk layout.
extern "C" __global__ void __launch_bounds__(256)
k_npm(const float* __restrict__ hin, float* __restrict__ hout,
      const float* __restrict__ wfp, const float* __restrict__ wsm,
      unsigned short* __restrict__ projd_pk, unsigned short* __restrict__ projs_pk,
      const float* __restrict__ aggr, float* __restrict__ aggr_z,
      const float* __restrict__ invc,
      const float* __restrict__ musum, const float* __restrict__ sqsum,
      const float* __restrict__ gamma, const float* __restrict__ beta) {
  __shared__ float hl[16][68];  // +4 pad: A-frag b128 reads land 4 lanes/bank max
  const int tid = threadIdx.x;
  const int lane = tid & 63;
  const int w = tid >> 6;  // 0..3: combo (Wf-dst, Wf-src, Ws-dst, Ws-src)
  const int i0 = blockIdx.x * 16;

  // stage 1: elementwise update, stash to LDS
  {
    const int k = tid & 63;  // this thread's feature
    const float mu = musum[k] * (1.0f / N_NODES);
    const float var = sqsum[k] * (1.0f / N_NODES) - mu * mu;
    const float r = gamma[k] * rsqrtf(var + BN_EPS);
    const float sh = beta[k] - mu * r;
#pragma unroll
    for (int jj = 0; jj < 4; ++jj) {
      const int row = (tid >> 6) + jj * 4;
      const int ii = i0 + row;
      float hv = hin[(size_t)ii * D1 + k];
      const float av = aggr[(size_t)ii * D1 + k] * invc[ii];
      hv = fmaxf(hv + fmaf(av, r, sh), 0.0f);
      hout[(size_t)ii * D1 + k] = hv;
      aggr_z[(size_t)ii * D1 + k] = 0.0f;
      hl[row][k] = hv;
    }
  }
  __syncthreads();

  // stage 2: per-wave combo GEMM
  const float* W = (w < 2) ? wfp : wsm;
  const int roff = (w & 1) * 64;
  unsigned short* pk = (w & 1) ? projs_pk : projd_pk;
  const int slot = (w < 2) ? 0 : 4;
  const int col = lane & 15;   // A: node row; B/D: feature col (per-operand conventions)
  const int quad = lane >> 4;

  // B fragments: B[k][f] = W[(roff+k)*64 + f], f-tile ft covers f = ft*16+col,
  // k-slice kh covers k = kh*32 + quad*8 + j  (matches k_init wprep convention)
  bf16x8 Bf[4][2];
#pragma unroll
  for (int ft = 0; ft < 4; ++ft)
#pragma unroll
    for (int kh = 0; kh < 2; ++kh) {
      bf16x8 bv;
#pragma unroll
      for (int j = 0; j < 8; ++j) {
        const float v = W[(size_t)(roff + kh * 32 + quad * 8 + j) * D1 + ft * 16 + col];
        ((unsigned short*)&bv)[j] = f2bf(v);
      }
      Bf[ft][kh] = bv;
    }

  // A fragments from LDS: lane holds A[row=col][k = kh*32 + quad*8 + j]
  bf16x8 A0, A1;
  {
    const float4* hr0 = (const float4*)&hl[col][quad * 8];
    const float4* hr1 = (const float4*)&hl[col][32 + quad * 8];
    const float4 a0 = hr0[0], a1 = hr0[1];
    const float4 b0 = hr1[0], b1 = hr1[1];
    ((unsigned short*)&A0)[0] = f2bf(a0.x); ((unsigned short*)&A0)[1] = f2bf(a0.y);
    ((unsigned short*)&A0)[2] = f2bf(a0.z); ((unsigned short*)&A0)[3] = f2bf(a0.w);
    ((unsigned short*)&A0)[4] = f2bf(a1.x); ((unsigned short*)&A0)[5] = f2bf(a1.y);
    ((unsigned short*)&A0)[6] = f2bf(a1.z); ((unsigned short*)&A0)[7] = f2bf(a1.w);
    ((unsigned short*)&A1)[0] = f2bf(b0.x); ((unsigned short*)&A1)[1] = f2bf(b0.y);
    ((unsigned short*)&A1)[2] = f2bf(b0.z); ((unsigned short*)&A1)[3] = f2bf(b0.w);
    ((unsigned short*)&A1)[4] = f2bf(b1.x); ((unsigned short*)&A1)[5] = f2bf(b1.y);
    ((unsigned short*)&A1)[6] = f2bf(b1.z); ((unsigned short*)&A1)[7] = f2bf(b1.w);
  }

  // 4 feature-tiles: D[node=quad*4+r][f=ft*16+col]; pk offset = (f>>2)*8+(f&3)+slot
#pragma unroll
  for (int ft = 0; ft < 4; ++ft) {
    f32x4 c = {0.0f, 0.0f, 0.0f, 0.0f};
    c = __builtin_amdgcn_mfma_f32_16x16x32_bf16(A0, Bf[ft][0], c, 0, 0, 0);
    c = __builtin_amdgcn_mfma_f32_16x16x32_bf16(A1, Bf[ft][1], c, 0, 0, 0);
    const int boff = (ft * 4 + (col >> 2)) * 8 + (col & 3) + slot;
#pragma unroll
    for (int r = 0; r < 4; ++r)
      pk[(size_t)(i0 + quad * 4 + r) * 128 + boff] = f2bf(c[r]);
  }
}

// ---------------- MFMA edge kernel: 4 waves/block, 1 tile per wave ----------
extern "C" __global__ void __launch_bounds__(256)
k_edgemm(const unsigned short* __restrict__ projd_pk,
         const unsigned short* __restrict__ projs_pk,
         const unsigned short* __restrict__ eapb,
         const int2* __restrict__ ds2,
         const unsigned short* __restrict__ Bp,
         const float* __restrict__ bfp, const float* __restrict__ bsp,
         float* __restrict__ aggr, float* __restrict__ musum,
         float* __restrict__ sqsum) {
  const int lane = threadIdx.x & 63;
  const int wv = threadIdx.x >> 6;
  const int col = lane & 15;
  const int quad = lane >> 4;
  __shared__ float mlds[4][16][68];

  const int vbid = (blockIdx.x & 7) * 938 + (blockIdx.x >> 3);
  if (blockIdx.x == 0 && wv == 0) {  // zero stats accumulators for k_stats
    musum[lane] = 0.0f;
    sqsum[lane] = 0.0f;
  }
  if (vbid >= EDGE_BLOCKS) return;

  const int t = vbid * 4 + wv;  // tile id; exactly NTILES waves
  const int base = t * 16;

  // independent streamed loads — all in flight together
  const int4 p01 = *(const int4*)(ds2 + base + quad * 4);      // edges r=0,1
  const int4 p23 = *(const int4*)(ds2 + base + quad * 4 + 2);  // edges r=2,3
  const int dr[4] = {p01.x, p01.z, p23.x, p23.z};
  const int sr[4] = {p01.y, p01.w, p23.y, p23.w};
  const bf16x8 Af0 = *(const bf16x8*)(eapb + ((size_t)(base + col) << 6) + quad * 8);
  const bf16x8 Af1 = *(const bf16x8*)(eapb + ((size_t)(base + col) << 6) + 32 + quad * 8);

  bf16x8 Bf[2][2][4];
#pragma unroll
  for (int m = 0; m < 2; ++m)
#pragma unroll
    for (int tt = 0; tt < 2; ++tt)
#pragma unroll
      for (int n = 0; n < 4; ++n)
        Bf[m][tt][n] = *(const bf16x8*)(Bp + ((((m * 2 + tt) * 4 + n) * 64 + lane) * 8));

  const f32x4 bf4 = *(const f32x4*)(bfp + col * 4);
  const f32x4 bs4 = *(const f32x4*)(bsp + col * 4);

  // C init from packed bf16 projections: 2 gathered 16B loads per edge row
  f32x4 aF[4], aS[4];
#pragma unroll
  for (int r = 0; r < 4; ++r) {
    const int d = dr[r];
    const int s = sr[r];
    const u16x8 pd = *(const u16x8*)(projd_pk + (size_t)d * 128 + col * 8);
    const u16x8 ss = *(const u16x8*)(projs_pk + (size_t)s * 128 + col * 8);
#pragma unroll
    for (int n = 0; n < 4; ++n) {
      aF[n][r] = bfu(pd[n]) + bfu(ss[n]) + bf4[n];
      aS[n][r] = bfu(pd[n + 4]) + bfu(ss[n + 4]) + bs4[n];
    }
  }

#pragma unroll
  for (int n = 0; n < 4; ++n) {
    aF[n] = __builtin_amdgcn_mfma_f32_16x16x32_bf16(Af0, Bf[0][0][n], aF[n], 0, 0, 0);
    aF[n] = __builtin_amdgcn_mfma_f32_16x16x32_bf16(Af1, Bf[0][1][n], aF[n], 0, 0, 0);
    aS[n] = __builtin_amdgcn_mfma_f32_16x16x32_bf16(Af0, Bf[1][0][n], aS[n], 0, 0, 0);
    aS[n] = __builtin_amdgcn_mfma_f32_16x16x32_bf16(Af1, Bf[1][1][n], aS[n], 0, 0, 0);
  }

  // epilogue: m = sigmoid(af) * softplus(as) -> LDS tile
#pragma unroll
  for (int r = 0; r < 4; ++r) {
    f32x4 mv;
#pragma unroll
    for (int n = 0; n < 4; ++n) {
      const float af = aF[n][r];
      const float as = aS[n][r];
      const float sg = __builtin_amdgcn_rcpf(1.0f + __expf(-af));
      const float sp = fmaxf(as, 0.0f) + __logf(1.0f + __expf(-fabsf(as)));
      mv[n] = sg * sp;
    }
    *(f32x4*)&mlds[wv][quad * 4 + r][col * 4] = mv;
  }
  __builtin_amdgcn_wave_barrier();

  // segmented reduce over the 16 dst-sorted CSR rows (raw sums; mean later)
  float sum = 0.0f;
  int dcur = ds2[base].x;
#pragma unroll
  for (int p = 0; p < 16; ++p) {
    sum += mlds[wv][p][lane];
    const int dnxt = (p < 15) ? ds2[base + p + 1].x : -1;
    if (dnxt != dcur) {
      atomicAdd(&aggr[(size_t)dcur * D1 + lane], sum);
      sum = 0.0f;
      dcur = dnxt;
    }
  }
}

// ---------------- BN stats over aggr*invc ----------------
extern "C" __global__ void __launch_bounds__(256)
k_stats(const float* __restrict__ aggr, const float* __restrict__ invc,
        float* __restrict__ musum, float* __restrict__ sqsum) {
  const int j = threadIdx.x & 63;
  const int rid = (blockIdx.x * blockDim.x + threadIdx.x) >> 6;
  const int rstr = (gridDim.x * blockDim.x) >> 6;
  float s = 0.0f, sq = 0.0f;
  for (int i = rid; i < N_NODES; i += rstr) {
    const float v = aggr[(size_t)i * D1 + j] * invc[i];
    s += v;
    sq = fmaf(v, v, sq);
  }
  __shared__ float ls[256], lq[256];
  ls[threadIdx.x] = s;
  lq[threadIdx.x] = sq;
  __syncthreads();
  if (threadIdx.x < 64) {
    s = ls[j] + ls[64 + j] + ls[128 + j] + ls[192 + j];
    sq = lq[j] + lq[64 + j] + lq[128 + j] + lq[192 + j];
    atomicAdd(&musum[j], s);
    atomicAdd(&sqsum[j], sq);
  }
}

// ---------------- fused pool (final BN update) + MLP chain ------------------
extern "C" __global__ void __launch_bounds__(256)
k_poolmlp(const float* __restrict__ h, const float* __restrict__ aggr,
          const float* __restrict__ invc,
          const float* __restrict__ musum, const float* __restrict__ sqsum,
          const float* __restrict__ gamma, const float* __restrict__ beta,
          const int* __restrict__ grp,
          const float* __restrict__ lin1_w, const float* __restrict__ lin1_b,
          const float* __restrict__ fc_w, const float* __restrict__ fc_b,
          const float* __restrict__ lin2_w, const float* __restrict__ lin2_b,
          float* __restrict__ out) {
  const int g = blockIdx.x;
  const int lane = threadIdx.x & 63;
  const int wv = threadIdx.x >> 6;
  const float mu = musum[lane] * (1.0f / N_NODES);
  const float var = sqsum[lane] * (1.0f / N_NODES) - mu * mu;
  const float r = gamma[lane] * rsqrtf(var + BN_EPS);
  const float sh = beta[lane] - mu * r;
  const int s = grp[g], e = grp[g + 1];
  float acc = 0.0f;
  for (int i = s + wv; i < e; i += 4) {
    const float hv = h[(size_t)i * D1 + lane];
    const float av = aggr[(size_t)i * D1 + lane] * invc[i];
    acc += fmaxf(hv + fmaf(av, r, sh), 0.0f);
  }
  __shared__ float red[4][64];
  __shared__ float vin[64];
  red[wv][lane] = acc;
  __syncthreads();
  const int j = threadIdx.x;
  float v = 0.0f;
  if (j < 64) {
    const float inv = 1.0f / fmaxf((float)(e - s), 1.0f);
    v = (red[0][j] + red[1][j] + red[2][j] + red[3][j]) * inv;
  }
  for (int layer = 0; layer < 3; ++layer) {
    if (j < 64) vin[j] = v;
    __syncthreads();
    if (j < 64) {
      const float* W;
      const float* B;
      if (layer == 0) {
        W = lin1_w;
        B = lin1_b;
      } else {
        W = fc_w + (size_t)(layer - 1) * D1 * D1;
        B = fc_b + (size_t)(layer - 1) * D1;
      }
      float a2 = B[j];
#pragma unroll 16
      for (int k = 0; k < D1; ++k) a2 = fmaf(vin[k], W[k * D1 + j], a2);
      v = fmaxf(a2, 0.0f);
    }
    __syncthreads();
  }
  if (j < 64) {
    float p = v * lin2_w[j];
#pragma unroll
    for (int off = 32; off > 0; off >>= 1) p += __shfl_down(p, off);
    if (j == 0) out[g] = p + lin2_b[0];
  }
}

extern "C" void kernel_launch(void* const* d_in, const int* in_sizes, int n_in,
                              void* d_out, int out_size, void* d_ws, size_t ws_size,
                              hipStream_t stream) {
  const float* x        = (const float*)d_in[0];
  const float* ea       = (const float*)d_in[1];
  const float* lin0_w   = (const float*)d_in[2];
  const float* lin0_b   = (const float*)d_in[3];
  const float* conv_wf  = (const float*)d_in[4];
  const float* conv_bf  = (const float*)d_in[5];
  const float* conv_ws  = (const float*)d_in[6];
  const float* conv_bs  = (const float*)d_in[7];
  const float* bn_gamma = (const float*)d_in[8];
  const float* bn_beta  = (const float*)d_in[9];
  const float* lin1_w   = (const float*)d_in[10];
  const float* lin1_b   = (const float*)d_in[11];
  const float* fc_w     = (const float*)d_in[12];
  const float* fc_b     = (const float*)d_in[13];
  const float* lin2_w   = (const float*)d_in[14];
  const float* lin2_b   = (const float*)d_in[15];
  const int*   ei       = (const int*)d_in[16];
  const int*   batch    = (const int*)d_in[17];

  uintptr_t p = (uintptr_t)d_ws;
  auto alloc = [&](size_t bytes) {
    p = (p + 255) & ~(size_t)255;
    void* r = (void*)p;
    p += bytes;
    return r;
  };
  float* h0     = (float*)alloc((size_t)N_NODES * 64 * 4);
  float* h1     = (float*)alloc((size_t)N_NODES * 64 * 4);
  unsigned short* projd_pk = (unsigned short*)alloc((size_t)N_NODES * 128 * 2);
  unsigned short* projs_pk = (unsigned short*)alloc((size_t)N_NODES * 128 * 2);
  float* aggrA  = (float*)alloc((size_t)N_NODES * 64 * 4);
  float* aggrB  = (float*)alloc((size_t)N_NODES * 64 * 4);
  float* musum  = (float*)alloc(128 * 4);
  float* sqsum  = musum + 64;
  float* invc   = (float*)alloc((size_t)N_NODES * 4);
  int*   cnt    = (int*)alloc((size_t)N_NODES * 4);
  int*   lpre   = (int*)alloc((size_t)N_NODES * 4);
  int*   ptot   = (int*)alloc((size_t)SCAN_BLOCKS * 4);
  int*   wptr   = (int*)alloc((size_t)N_NODES * 4);
  int2*  ds2    = (int2*)alloc((size_t)N_EDGES * 8);
  int*   grp    = (int*)alloc((size_t)(NG + 1) * 4);
  unsigned short* eapb = (unsigned short*)alloc((size_t)N_EDGES * 64 * 2);
  unsigned short* Bp   = (unsigned short*)alloc((size_t)NL * 16 * 64 * 8 * 2);

  hipMemsetAsync(cnt, 0, N_NODES * sizeof(int), stream);
  k_init<<<LIN0_BLOCKS + CNT_BLOCKS + WPREP_BLOCKS, 256, 0, stream>>>(
      x, lin0_w, lin0_b, h0, ei, cnt, conv_wf, conv_ws, Bp);
  k_scan1<<<SCAN_BLOCKS, 256, 0, stream>>>(cnt, lpre, ptot);
  k_scan23<<<SCAN_BLOCKS, 256, 0, stream>>>(cnt, lpre, ptot, batch, wptr, invc, grp);
  // fused: CSR build + bf16 pack + nodeproj(l=0)  (baseline structure)
  k_build<<<BUILD_BLOCKS + NP_BLOCKS, 256, 0, stream>>>(
      ei, wptr, ds2, ea, eapb, h0, conv_wf, conv_ws, projd_pk, projs_pk, aggrA);

  float* aggr_of[NL] = {aggrA, aggrB, aggrA};
  const float* hin_of[NL]  = {h0, h0, h1};
  float* hout_of[NL]       = {h0, h1, h0};

  for (int l = 0; l < NL; ++l) {
    const float* wfl = conv_wf + (size_t)l * ZD * D1;
    const float* wsl = conv_ws + (size_t)l * ZD * D1;
    if (l > 0)
      k_npm<<<NPM_BLOCKS, 256, 0, stream>>>(
          hin_of[l], hout_of[l], wfl, wsl, projd_pk, projs_pk,
          aggr_of[l - 1], aggr_of[l], invc, musum, sqsum,
          bn_gamma + (size_t)(l - 1) * D1, bn_beta + (size_t)(l - 1) * D1);
    k_edgemm<<<EDGE_GRID, 256, 0, stream>>>(
        projd_pk, projs_pk, eapb, ds2,
        Bp + (size_t)l * 16 * 64 * 8,
        conv_bf + (size_t)l * D1, conv_bs + (size_t)l * D1,
        aggr_of[l], musum, sqsum);
    k_stats<<<256, 256, 0, stream>>>(aggr_of[l], invc, musum, sqsum);
  }

  k_poolmlp<<<NG, 256, 0, stream>>>(h0, aggr_of[2], invc, musum, sqsum,
                                    bn_gamma + (size_t)2 * D1, bn_beta + (size_t)2 * D1,
                                    grp, lin1_w, lin1_b, fc_w, fc_b,
                                    lin2_w, lin2_b, (float*)d_out);
}

// Round 9
// 585.078 us; speedup vs baseline: 3.6149x; 1.0160x over previous
//
#include <hip/hip_runtime.h>
#include <hip/hip_bf16.h>

#define N_NODES 30000
#define N_EDGES 480000
#define NFEAT 92
#define EFEAT 50
#define D1 64
#define ZD 178
#define NL 3
#define NG 256
#define BN_EPS 1e-5f
#define NTILES (N_EDGES / 16)     // 30000 tiles, 1 per wave
#define EDGE_BLOCKS 7500          // logical blocks (4 waves each)
#define EDGE_GRID 7504            // 8 XCDs x 938, guard vbid < 7500

#define LIN0_BLOCKS 512
#define CNT_BLOCKS 1875    // E / 256
#define WPREP_BLOCKS 96    // NL*16*64*8 / 256
#define SCAN_BLOCKS ((N_NODES + 255) / 256)  // 118
#define BUILD_BLOCKS 1875  // E / 256
#define NPM_BLOCKS 1875    // MFMA nodeproj: N_NODES/16 tiles, 1 per block

typedef __attribute__((ext_vector_type(8))) short bf16x8;
typedef __attribute__((ext_vector_type(8))) unsigned short u16x8;
typedef __attribute__((ext_vector_type(4))) unsigned short u16x4;
typedef __attribute__((ext_vector_type(4))) float f32x4;

static __device__ __forceinline__ unsigned short f2bf(float v) {
  __hip_bfloat16 b = __float2bfloat16(v);
  return *(unsigned short*)&b;
}
static __device__ __forceinline__ float bfu(unsigned short u) {
  union { unsigned int i; float f; } c;
  c.i = ((unsigned int)u) << 16;
  return c.f;
}

// ---------------- R8-proven MFMA nodeproj GEMM stage ----------------
// Per-wave combo (Wf/Ws x dst/src): [16 nodes x 64 feats] via 4 f-tiles x 2
// K-slice MFMAs; bf16 store into packed pk layout.
// A: row(node)=lane&15, k=(lane>>4)*8+j ; B: col(feat)=ft*16+(lane&15), same k;
// D: node=(lane>>4)*4+r, feat=ft*16+(lane&15); boff == (f>>2)*8+(f&3)+slot.
static __device__ __forceinline__ void npm_gemm(
    int i0, const float* __restrict__ wfp, const float* __restrict__ wsm,
    unsigned short* __restrict__ projd_pk, unsigned short* __restrict__ projs_pk,
    const float (*hl)[68]) {
  const int lane = threadIdx.x & 63;
  const int w = threadIdx.x >> 6;  // 0..3: combo (Wf-dst, Wf-src, Ws-dst, Ws-src)
  const float* W = (w < 2) ? wfp : wsm;
  const int roff = (w & 1) * 64;
  unsigned short* pk = (w & 1) ? projs_pk : projd_pk;
  const int slot = (w < 2) ? 0 : 4;
  const int col = lane & 15;
  const int quad = lane >> 4;

  bf16x8 Bf[4][2];
#pragma unroll
  for (int ft = 0; ft < 4; ++ft)
#pragma unroll
    for (int kh = 0; kh < 2; ++kh) {
      bf16x8 bv;
#pragma unroll
      for (int j = 0; j < 8; ++j) {
        const float v = W[(size_t)(roff + kh * 32 + quad * 8 + j) * D1 + ft * 16 + col];
        ((unsigned short*)&bv)[j] = f2bf(v);
      }
      Bf[ft][kh] = bv;
    }

  bf16x8 A0, A1;
  {
    const float4* hr0 = (const float4*)&hl[col][quad * 8];
    const float4* hr1 = (const float4*)&hl[col][32 + quad * 8];
    const float4 a0 = hr0[0], a1 = hr0[1];
    const float4 b0 = hr1[0], b1 = hr1[1];
    ((unsigned short*)&A0)[0] = f2bf(a0.x); ((unsigned short*)&A0)[1] = f2bf(a0.y);
    ((unsigned short*)&A0)[2] = f2bf(a0.z); ((unsigned short*)&A0)[3] = f2bf(a0.w);
    ((unsigned short*)&A0)[4] = f2bf(a1.x); ((unsigned short*)&A0)[5] = f2bf(a1.y);
    ((unsigned short*)&A0)[6] = f2bf(a1.z); ((unsigned short*)&A0)[7] = f2bf(a1.w);
    ((unsigned short*)&A1)[0] = f2bf(b0.x); ((unsigned short*)&A1)[1] = f2bf(b0.y);
    ((unsigned short*)&A1)[2] = f2bf(b0.z); ((unsigned short*)&A1)[3] = f2bf(b0.w);
    ((unsigned short*)&A1)[4] = f2bf(b1.x); ((unsigned short*)&A1)[5] = f2bf(b1.y);
    ((unsigned short*)&A1)[6] = f2bf(b1.z); ((unsigned short*)&A1)[7] = f2bf(b1.w);
  }

#pragma unroll
  for (int ft = 0; ft < 4; ++ft) {
    f32x4 c = {0.0f, 0.0f, 0.0f, 0.0f};
    c = __builtin_amdgcn_mfma_f32_16x16x32_bf16(A0, Bf[ft][0], c, 0, 0, 0);
    c = __builtin_amdgcn_mfma_f32_16x16x32_bf16(A1, Bf[ft][1], c, 0, 0, 0);
    const int boff = (ft * 4 + (col >> 2)) * 8 + (col & 3) + slot;
#pragma unroll
    for (int r = 0; r < 4; ++r)
      pk[(size_t)(i0 + quad * 4 + r) * 128 + boff] = f2bf(c[r]);
  }
}

// ---------------- init: lin0 + dst counts + B fragments (block-range split) --
extern "C" __global__ void __launch_bounds__(256)
k_init(const float* __restrict__ x, const float* __restrict__ w,
       const float* __restrict__ b, float* __restrict__ h,
       const int* __restrict__ ei, int* __restrict__ cnt,
       const float* __restrict__ conv_wf, const float* __restrict__ conv_ws,
       unsigned short* __restrict__ Bp) {
  const int blk = blockIdx.x;
  if (blk < LIN0_BLOCKS) {
    const int lane = threadIdx.x & 63;
    const int wave = (blk * 256 + threadIdx.x) >> 6;
    const int nw = (LIN0_BLOCKS * 256) >> 6;
    float wreg[NFEAT];
#pragma unroll
    for (int k = 0; k < NFEAT; ++k) wreg[k] = w[k * D1 + lane];
    const float bj = b[lane];
    for (int i = wave; i < N_NODES; i += nw) {
      const float2* xr = (const float2*)(x + (size_t)i * NFEAT);
      float acc = bj;
#pragma unroll
      for (int k = 0; k < NFEAT / 2; ++k) {
        const float2 v = xr[k];
        acc = fmaf(v.x, wreg[2 * k], acc);
        acc = fmaf(v.y, wreg[2 * k + 1], acc);
      }
      h[(size_t)i * D1 + lane] = fmaxf(acc, 0.0f);
    }
  } else if (blk < LIN0_BLOCKS + CNT_BLOCKS) {
    const int e = (blk - LIN0_BLOCKS) * 256 + threadIdx.x;
    if (e < N_EDGES) atomicAdd(&cnt[ei[N_EDGES + e]], 1);
  } else {
    const int idx = (blk - LIN0_BLOCKS - CNT_BLOCKS) * 256 + threadIdx.x;
    const int j = idx & 7;
    const int lane = (idx >> 3) & 63;
    const int frag = (idx >> 9) & 15;  // (m*2+t)*4+n
    const int l = idx >> 13;
    const int n = frag & 3;
    const int t = (frag >> 2) & 1;
    const int m = frag >> 3;
    const int k = t * 32 + (lane >> 4) * 8 + j;
    const int feat = (lane & 15) * 4 + n;
    float v = 0.0f;
    if (k < EFEAT) {
      const float* W = (m == 0) ? conv_wf : conv_ws;
      v = W[(size_t)l * ZD * D1 + (size_t)(128 + k) * D1 + feat];
    }
    Bp[idx] = f2bf(v);
  }
}

// ---------------- scan phase 1: per-block partial sums ----------------
extern "C" __global__ void __launch_bounds__(256)
k_scan1(const int* __restrict__ cnt, int* __restrict__ lpre, int* __restrict__ ptot) {
  const int t = threadIdx.x;
  const int idx = blockIdx.x * 256 + t;
  const int v = (idx < N_NODES) ? cnt[idx] : 0;
  __shared__ int bs[256];
  bs[t] = v;
  __syncthreads();
  for (int off = 1; off < 256; off <<= 1) {
    int u = (t >= off) ? bs[t - off] : 0;
    __syncthreads();
    bs[t] += u;
    __syncthreads();
  }
  if (idx < N_NODES) lpre[idx] = bs[t] - v;
  if (t == 255) ptot[blockIdx.x] = bs[255];
}

// scan phase 2+3: redundant block-offset scan + wptr/invc/grp
extern "C" __global__ void __launch_bounds__(256)
k_scan23(const int* __restrict__ cnt, const int* __restrict__ lpre,
         const int* __restrict__ ptot, const int* __restrict__ batch,
         int* __restrict__ wptr, float* __restrict__ invc,
         int* __restrict__ grp) {
  __shared__ int bs[128];
  const int t = threadIdx.x;
  if (t < 128) bs[t] = (t < SCAN_BLOCKS) ? ptot[t] : 0;
  __syncthreads();
  for (int off = 1; off < 128; off <<= 1) {
    int u = 0;
    if (t < 128 && t >= off) u = bs[t - off];
    __syncthreads();
    if (t < 128 && t >= off) bs[t] += u;
    __syncthreads();
  }
  const int idx = blockIdx.x * 256 + t;
  if (idx >= N_NODES) return;
  const int bid = idx >> 8;
  const int boff = (bid == 0) ? 0 : bs[bid - 1];
  wptr[idx] = boff + lpre[idx];
  invc[idx] = 1.0f / fmaxf((float)cnt[idx], 1.0f);
  const int bt = batch[idx];
  if (idx == 0)
    for (int g = 0; g <= bt; ++g) grp[g] = 0;
  else {
    const int pb = batch[idx - 1];
    for (int g = pb + 1; g <= bt; ++g) grp[g] = idx;
  }
  if (idx == N_NODES - 1)
    for (int g = bt + 1; g <= NG; ++g) grp[g] = N_NODES;
}

// ---------------- build: CSR scatter + bf16 pack + MFMA nodeproj0 -----------
// blocks [0, BUILD_BLOCKS): scatter+pack (unchanged, latency-bound streaming);
// blocks [BUILD_BLOCKS, +NPM_BLOCKS): R9 — MFMA nodeproj l=0 (16-node tiles,
// no BN), replacing the scalar 1024-block tail. Keeps the fusion/overlap that
// R1-R3 proved essential; MFMA work co-schedules with the pack's VMEM stalls.
extern "C" __global__ void __launch_bounds__(256)
k_build(const int* __restrict__ ei, int* __restrict__ wptr,
        int2* __restrict__ ds2, const float* __restrict__ ea,
        unsigned short* __restrict__ eapb,
        const float* __restrict__ h0, const float* __restrict__ wfl,
        const float* __restrict__ wsl, unsigned short* __restrict__ projd_pk,
        unsigned short* __restrict__ projs_pk, float* __restrict__ aggrA) {
  __shared__ __align__(16) float hl[16][68];  // union: lpos (1KB) / h tile (4.25KB)
  if (blockIdx.x >= BUILD_BLOCKS) {
    const int i0 = (blockIdx.x - BUILD_BLOCKS) * 16;
    const int tid = threadIdx.x;
    // stage 1: load h0 tile to LDS + zero aggrA (no BN at layer 0)
    {
      const int k = tid & 63;
#pragma unroll
      for (int jj = 0; jj < 4; ++jj) {
        const int row = (tid >> 6) + jj * 4;
        const int ii = i0 + row;
        const float hv = h0[(size_t)ii * D1 + k];
        aggrA[(size_t)ii * D1 + k] = 0.0f;
        hl[row][k] = hv;
      }
    }
    __syncthreads();
    npm_gemm(i0, wfl, wsl, projd_pk, projs_pk, hl);
    return;
  }
  int* lpos = (int*)hl;
  const int e0 = blockIdx.x * 256;
  {
    const int e = e0 + threadIdx.x;
    const int d = ei[N_EDGES + e];
    const int pos = atomicAdd(&wptr[d], 1);
    ds2[pos] = make_int2(d, ei[e]);  // one 8B scatter (half the sectors)
    lpos[threadIdx.x] = pos;
  }
  __syncthreads();
  const int l16 = threadIdx.x & 15;
  const int sub = threadIdx.x >> 4;  // 0..15
#pragma unroll
  for (int r = 0; r < 16; ++r) {
    const int eb = r * 16 + sub;
    const size_t ge = e0 + eb;
    const int pos = lpos[eb];
    unsigned short o0 = 0, o1 = 0, o2 = 0, o3 = 0;
    if (l16 < 12) {
      const float4 v = *(const float4*)(ea + ge * EFEAT + l16 * 4);
      o0 = f2bf(v.x); o1 = f2bf(v.y); o2 = f2bf(v.z); o3 = f2bf(v.w);
    } else if (l16 == 12) {
      const float2 v = *(const float2*)(ea + ge * EFEAT + 48);
      o0 = f2bf(v.x); o1 = f2bf(v.y);
    }
    u16x4 st;
    st[0] = o0; st[1] = o1; st[2] = o2; st[3] = o3;
    *(u16x4*)(eapb + ((size_t)pos << 6) + l16 * 4) = st;
  }
}

// ---------------- R8: MFMA node projection (layers 1,2) ----------------
// One 16-node tile per block. Stage 1: elementwise BN/residual/relu -> LDS
// (identical side effects: hout write, aggr_z zero). Stage 2: npm_gemm.
extern "C" __global__ void __launch_bounds__(256)
k_npm(const float* __restrict__ hin, float* __restrict__ hout,
      const float* __restrict__ wfp, const float* __restrict__ wsm,
      unsigned short* __restrict__ projd_pk, unsigned short* __restrict__ projs_pk,
      const float* __restrict__ aggr, float* __restrict__ aggr_z,
      const float* __restrict__ invc,
      const float* __restrict__ musum, const float* __restrict__ sqsum,
      const float* __restrict__ gamma, const float* __restrict__ beta) {
  __shared__ float hl[16][68];  // +4 pad
  const int tid = threadIdx.x;
  const int i0 = blockIdx.x * 16;

  // stage 1: elementwise update, stash to LDS
  {
    const int k = tid & 63;  // this thread's feature
    const float mu = musum[k] * (1.0f / N_NODES);
    const float var = sqsum[k] * (1.0f / N_NODES) - mu * mu;
    const float r = gamma[k] * rsqrtf(var + BN_EPS);
    const float sh = beta[k] - mu * r;
#pragma unroll
    for (int jj = 0; jj < 4; ++jj) {
      const int row = (tid >> 6) + jj * 4;
      const int ii = i0 + row;
      float hv = hin[(size_t)ii * D1 + k];
      const float av = aggr[(size_t)ii * D1 + k] * invc[ii];
      hv = fmaxf(hv + fmaf(av, r, sh), 0.0f);
      hout[(size_t)ii * D1 + k] = hv;
      aggr_z[(size_t)ii * D1 + k] = 0.0f;
      hl[row][k] = hv;
    }
  }
  __syncthreads();
  npm_gemm(i0, wfp, wsm, projd_pk, projs_pk, hl);
}

// ---------------- MFMA edge kernel: 4 waves/block, 1 tile per wave ----------
extern "C" __global__ void __launch_bounds__(256)
k_edgemm(const unsigned short* __restrict__ projd_pk,
         const unsigned short* __restrict__ projs_pk,
         const unsigned short* __restrict__ eapb,
         const int2* __restrict__ ds2,
         const unsigned short* __restrict__ Bp,
         const float* __restrict__ bfp, const float* __restrict__ bsp,
         float* __restrict__ aggr, float* __restrict__ musum,
         float* __restrict__ sqsum) {
  const int lane = threadIdx.x & 63;
  const int wv = threadIdx.x >> 6;
  const int col = lane & 15;
  const int quad = lane >> 4;
  __shared__ float mlds[4][16][68];

  const int vbid = (blockIdx.x & 7) * 938 + (blockIdx.x >> 3);
  if (blockIdx.x == 0 && wv == 0) {  // zero stats accumulators for k_stats
    musum[lane] = 0.0f;
    sqsum[lane] = 0.0f;
  }
  if (vbid >= EDGE_BLOCKS) return;

  const int t = vbid * 4 + wv;  // tile id; exactly NTILES waves
  const int base = t * 16;

  // independent streamed loads — all in flight together
  const int4 p01 = *(const int4*)(ds2 + base + quad * 4);      // edges r=0,1
  const int4 p23 = *(const int4*)(ds2 + base + quad * 4 + 2);  // edges r=2,3
  const int dr[4] = {p01.x, p01.z, p23.x, p23.z};
  const int sr[4] = {p01.y, p01.w, p23.y, p23.w};
  const bf16x8 Af0 = *(const bf16x8*)(eapb + ((size_t)(base + col) << 6) + quad * 8);
  const bf16x8 Af1 = *(const bf16x8*)(eapb + ((size_t)(base + col) << 6) + 32 + quad * 8);

  bf16x8 Bf[2][2][4];
#pragma unroll
  for (int m = 0; m < 2; ++m)
#pragma unroll
    for (int tt = 0; tt < 2; ++tt)
#pragma unroll
      for (int n = 0; n < 4; ++n)
        Bf[m][tt][n] = *(const bf16x8*)(Bp + ((((m * 2 + tt) * 4 + n) * 64 + lane) * 8));

  const f32x4 bf4 = *(const f32x4*)(bfp + col * 4);
  const f32x4 bs4 = *(const f32x4*)(bsp + col * 4);

  // C init from packed bf16 projections: 2 gathered 16B loads per edge row
  f32x4 aF[4], aS[4];
#pragma unroll
  for (int r = 0; r < 4; ++r) {
    const int d = dr[r];
    const int s = sr[r];
    const u16x8 pd = *(const u16x8*)(projd_pk + (size_t)d * 128 + col * 8);
    const u16x8 ss = *(const u16x8*)(projs_pk + (size_t)s * 128 + col * 8);
#pragma unroll
    for (int n = 0; n < 4; ++n) {
      aF[n][r] = bfu(pd[n]) + bfu(ss[n]) + bf4[n];
      aS[n][r] = bfu(pd[n + 4]) + bfu(ss[n + 4]) + bs4[n];
    }
  }

#pragma unroll
  for (int n = 0; n < 4; ++n) {
    aF[n] = __builtin_amdgcn_mfma_f32_16x16x32_bf16(Af0, Bf[0][0][n], aF[n], 0, 0, 0);
    aF[n] = __builtin_amdgcn_mfma_f32_16x16x32_bf16(Af1, Bf[0][1][n], aF[n], 0, 0, 0);
    aS[n] = __builtin_amdgcn_mfma_f32_16x16x32_bf16(Af0, Bf[1][0][n], aS[n], 0, 0, 0);
    aS[n] = __builtin_amdgcn_mfma_f32_16x16x32_bf16(Af1, Bf[1][1][n], aS[n], 0, 0, 0);
  }

  // epilogue: m = sigmoid(af) * softplus(as) -> LDS tile
#pragma unroll
  for (int r = 0; r < 4; ++r) {
    f32x4 mv;
#pragma unroll
    for (int n = 0; n < 4; ++n) {
      const float af = aF[n][r];
      const float as = aS[n][r];
      const float sg = __builtin_amdgcn_rcpf(1.0f + __expf(-af));
      const float sp = fmaxf(as, 0.0f) + __logf(1.0f + __expf(-fabsf(as)));
      mv[n] = sg * sp;
    }
    *(f32x4*)&mlds[wv][quad * 4 + r][col * 4] = mv;
  }
  __builtin_amdgcn_wave_barrier();

  // segmented reduce over the 16 dst-sorted CSR rows (raw sums; mean later)
  float sum = 0.0f;
  int dcur = ds2[base].x;
#pragma unroll
  for (int p = 0; p < 16; ++p) {
    sum += mlds[wv][p][lane];
    const int dnxt = (p < 15) ? ds2[base + p + 1].x : -1;
    if (dnxt != dcur) {
      atomicAdd(&aggr[(size_t)dcur * D1 + lane], sum);
      sum = 0.0f;
      dcur = dnxt;
    }
  }
}

// ---------------- BN stats over aggr*invc ----------------
extern "C" __global__ void __launch_bounds__(256)
k_stats(const float* __restrict__ aggr, const float* __restrict__ invc,
        float* __restrict__ musum, float* __restrict__ sqsum) {
  const int j = threadIdx.x & 63;
  const int rid = (blockIdx.x * blockDim.x + threadIdx.x) >> 6;
  const int rstr = (gridDim.x * blockDim.x) >> 6;
  float s = 0.0f, sq = 0.0f;
  for (int i = rid; i < N_NODES; i += rstr) {
    const float v = aggr[(size_t)i * D1 + j] * invc[i];
    s += v;
    sq = fmaf(v, v, sq);
  }
  __shared__ float ls[256], lq[256];
  ls[threadIdx.x] = s;
  lq[threadIdx.x] = sq;
  __syncthreads();
  if (threadIdx.x < 64) {
    s = ls[j] + ls[64 + j] + ls[128 + j] + ls[192 + j];
    sq = lq[j] + lq[64 + j] + lq[128 + j] + lq[192 + j];
    atomicAdd(&musum[j], s);
    atomicAdd(&sqsum[j], sq);
  }
}

// ---------------- fused pool (final BN update) + MLP chain ------------------
extern "C" __global__ void __launch_bounds__(256)
k_poolmlp(const float* __restrict__ h, const float* __restrict__ aggr,
          const float* __restrict__ invc,
          const float* __restrict__ musum, const float* __restrict__ sqsum,
          const float* __restrict__ gamma, const float* __restrict__ beta,
          const int* __restrict__ grp,
          const float* __restrict__ lin1_w, const float* __restrict__ lin1_b,
          const float* __restrict__ fc_w, const float* __restrict__ fc_b,
          const float* __restrict__ lin2_w, const float* __restrict__ lin2_b,
          float* __restrict__ out) {
  const int g = blockIdx.x;
  const int lane = threadIdx.x & 63;
  const int wv = threadIdx.x >> 6;
  const float mu = musum[lane] * (1.0f / N_NODES);
  const float var = sqsum[lane] * (1.0f / N_NODES) - mu * mu;
  const float r = gamma[lane] * rsqrtf(var + BN_EPS);
  const float sh = beta[lane] - mu * r;
  const int s = grp[g], e = grp[g + 1];
  float acc = 0.0f;
  for (int i = s + wv; i < e; i += 4) {
    const float hv = h[(size_t)i * D1 + lane];
    const float av = aggr[(size_t)i * D1 + lane] * invc[i];
    acc += fmaxf(hv + fmaf(av, r, sh), 0.0f);
  }
  __shared__ float red[4][64];
  __shared__ float vin[64];
  red[wv][lane] = acc;
  __syncthreads();
  const int j = threadIdx.x;
  float v = 0.0f;
  if (j < 64) {
    const float inv = 1.0f / fmaxf((float)(e - s), 1.0f);
    v = (red[0][j] + red[1][j] + red[2][j] + red[3][j]) * inv;
  }
  for (int layer = 0; layer < 3; ++layer) {
    if (j < 64) vin[j] = v;
    __syncthreads();
    if (j < 64) {
      const float* W;
      const float* B;
      if (layer == 0) {
        W = lin1_w;
        B = lin1_b;
      } else {
        W = fc_w + (size_t)(layer - 1) * D1 * D1;
        B = fc_b + (size_t)(layer - 1) * D1;
      }
      float a2 = B[j];
#pragma unroll 16
      for (int k = 0; k < D1; ++k) a2 = fmaf(vin[k], W[k * D1 + j], a2);
      v = fmaxf(a2, 0.0f);
    }
    __syncthreads();
  }
  if (j < 64) {
    float p = v * lin2_w[j];
#pragma unroll
    for (int off = 32; off > 0; off >>= 1) p += __shfl_down(p, off);
    if (j == 0) out[g] = p + lin2_b[0];
  }
}

extern "C" void kernel_launch(void* const* d_in, const int* in_sizes, int n_in,
                              void* d_out, int out_size, void* d_ws, size_t ws_size,
                              hipStream_t stream) {
  const float* x        = (const float*)d_in[0];
  const float* ea       = (const float*)d_in[1];
  const float* lin0_w   = (const float*)d_in[2];
  const float* lin0_b   = (const float*)d_in[3];
  const float* conv_wf  = (const float*)d_in[4];
  const float* conv_bf  = (const float*)d_in[5];
  const float* conv_ws  = (const float*)d_in[6];
  const float* conv_bs  = (const float*)d_in[7];
  const float* bn_gamma = (const float*)d_in[8];
  const float* bn_beta  = (const float*)d_in[9];
  const float* lin1_w   = (const float*)d_in[10];
  const float* lin1_b   = (const float*)d_in[11];
  const float* fc_w     = (const float*)d_in[12];
  const float* fc_b     = (const float*)d_in[13];
  const float* lin2_w   = (const float*)d_in[14];
  const float* lin2_b   = (const float*)d_in[15];
  const int*   ei       = (const int*)d_in[16];
  const int*   batch    = (const int*)d_in[17];

  uintptr_t p = (uintptr_t)d_ws;
  auto alloc = [&](size_t bytes) {
    p = (p + 255) & ~(size_t)255;
    void* r = (void*)p;
    p += bytes;
    return r;
  };
  float* h0     = (float*)alloc((size_t)N_NODES * 64 * 4);
  float* h1     = (float*)alloc((size_t)N_NODES * 64 * 4);
  unsigned short* projd_pk = (unsigned short*)alloc((size_t)N_NODES * 128 * 2);
  unsigned short* projs_pk = (unsigned short*)alloc((size_t)N_NODES * 128 * 2);
  float* aggrA  = (float*)alloc((size_t)N_NODES * 64 * 4);
  float* aggrB  = (float*)alloc((size_t)N_NODES * 64 * 4);
  float* musum  = (float*)alloc(128 * 4);
  float* sqsum  = musum + 64;
  float* invc   = (float*)alloc((size_t)N_NODES * 4);
  int*   cnt    = (int*)alloc((size_t)N_NODES * 4);
  int*   lpre   = (int*)alloc((size_t)N_NODES * 4);
  int*   ptot   = (int*)alloc((size_t)SCAN_BLOCKS * 4);
  int*   wptr   = (int*)alloc((size_t)N_NODES * 4);
  int2*  ds2    = (int2*)alloc((size_t)N_EDGES * 8);
  int*   grp    = (int*)alloc((size_t)(NG + 1) * 4);
  unsigned short* eapb = (unsigned short*)alloc((size_t)N_EDGES * 64 * 2);
  unsigned short* Bp   = (unsigned short*)alloc((size_t)NL * 16 * 64 * 8 * 2);

  hipMemsetAsync(cnt, 0, N_NODES * sizeof(int), stream);
  k_init<<<LIN0_BLOCKS + CNT_BLOCKS + WPREP_BLOCKS, 256, 0, stream>>>(
      x, lin0_w, lin0_b, h0, ei, cnt, conv_wf, conv_ws, Bp);
  k_scan1<<<SCAN_BLOCKS, 256, 0, stream>>>(cnt, lpre, ptot);
  k_scan23<<<SCAN_BLOCKS, 256, 0, stream>>>(cnt, lpre, ptot, batch, wptr, invc, grp);
  // fused: CSR build + bf16 pack + MFMA nodeproj(l=0)
  k_build<<<BUILD_BLOCKS + NPM_BLOCKS, 256, 0, stream>>>(
      ei, wptr, ds2, ea, eapb, h0, conv_wf, conv_ws, projd_pk, projs_pk, aggrA);

  float* aggr_of[NL] = {aggrA, aggrB, aggrA};
  const float* hin_of[NL]  = {h0, h0, h1};
  float* hout_of[NL]       = {h0, h1, h0};

  for (int l = 0; l < NL; ++l) {
    const float* wfl = conv_wf + (size_t)l * ZD * D1;
    const float* wsl = conv_ws + (size_t)l * ZD * D1;
    if (l > 0)
      k_npm<<<NPM_BLOCKS, 256, 0, stream>>>(
          hin_of[l], hout_of[l], wfl, wsl, projd_pk, projs_pk,
          aggr_of[l - 1], aggr_of[l], invc, musum, sqsum,
          bn_gamma + (size_t)(l - 1) * D1, bn_beta + (size_t)(l - 1) * D1);
    k_edgemm<<<EDGE_GRID, 256, 0, stream>>>(
        projd_pk, projs_pk, eapb, ds2,
        Bp + (size_t)l * 16 * 64 * 8,
        conv_bf + (size_t)l * D1, conv_bs + (size_t)l * D1,
        aggr_of[l], musum, sqsum);
    k_stats<<<256, 256, 0, stream>>>(aggr_of[l], invc, musum, sqsum);
  }

  k_poolmlp<<<NG, 256, 0, stream>>>(h0, aggr_of[2], invc, musum, sqsum,
                                    bn_gamma + (size_t)2 * D1, bn_beta + (size_t)2 * D1,
                                    grp, lin1_w, lin1_b, fc_w, fc_b,
                                    lin2_w, lin2_b, (float*)d_out);
}